// Round 5
// baseline (1095.862 us; speedup 1.0000x reference)
//
#include <hip/hip_runtime.h>
#include <math.h>
#include <stdint.h>

#define S_LEN 2048
#define DMODEL 1024
#define NH 8
#define DK_ 128
#define DV_ 128
#define KD_ 1024
#define KCONV 4
#define NWIN 128
#define PRE_STRIDE 6784  // per (w,h): khat 2048 | qhat 2048 | kchk 2048 | Mt 256 | N 256 | Pbar 128

typedef short bf16x8 __attribute__((ext_vector_type(8)));
typedef float f32x4 __attribute__((ext_vector_type(4)));

__device__ __forceinline__ uint16_t f2bf(float f) {  // RNE
  uint32_t u = __float_as_uint(f);
  u += 0x7FFF + ((u >> 16) & 1);
  return (uint16_t)(u >> 16);
}

__device__ __forceinline__ void glds16(const uint16_t* g, uint16_t* l) {
  __builtin_amdgcn_global_load_lds(
      (const __attribute__((address_space(1))) void*)g,
      (__attribute__((address_space(3))) void*)l, 16, 0, 0);
}

__device__ __forceinline__ float dot4(float4 a, float4 b) {
  return fmaf(a.w, b.w, fmaf(a.z, b.z, fmaf(a.y, b.y, a.x * b.x)));
}
__device__ __forceinline__ float4 f4add(float4 a, float4 b) {
  float4 r; r.x = a.x + b.x; r.y = a.y + b.y; r.z = a.z + b.z; r.w = a.w + b.w; return r;
}
__device__ __forceinline__ float4 f4sub(float4 a, float4 b) {
  float4 r; r.x = a.x - b.x; r.y = a.y - b.y; r.z = a.z - b.z; r.w = a.w - b.w; return r;
}
__device__ __forceinline__ float4 f4mul(float4 a, float4 b) {
  float4 r; r.x = a.x * b.x; r.y = a.y * b.y; r.z = a.z * b.z; r.w = a.w * b.w; return r;
}
__device__ __forceinline__ float4 f4s(float4 a, float s) {
  float4 r; r.x = a.x * s; r.y = a.y * s; r.z = a.z * s; r.w = a.w * s; return r;
}
__device__ __forceinline__ float4 f4fma(float4 a, float s, float4 c) {
  float4 r; r.x = fmaf(a.x, s, c.x); r.y = fmaf(a.y, s, c.y);
  r.z = fmaf(a.z, s, c.z); r.w = fmaf(a.w, s, c.w); return r;
}
__device__ __forceinline__ float4 f4exp(float4 a) {
  float4 r; r.x = expf(a.x); r.y = expf(a.y); r.z = expf(a.z); r.w = expf(a.w); return r;
}

#define DPPADD(x, ctrl) \
  x += __int_as_float(__builtin_amdgcn_update_dpp(0, __float_as_int(x), ctrl, 0xF, 0xF, true))

__device__ __forceinline__ void row16_sum2(float& a, float& b) {
  DPPADD(a, 0xB1); DPPADD(b, 0xB1);
  DPPADD(a, 0x4E); DPPADD(b, 0x4E);
  DPPADD(a, 0x141); DPPADD(b, 0x141);
  DPPADD(a, 0x140); DPPADD(b, 0x140);
}
__device__ __forceinline__ void row16_arr16(float* x) {
#pragma unroll
  for (int i = 0; i < 16; i++) DPPADD(x[i], 0xB1);
#pragma unroll
  for (int i = 0; i < 16; i++) DPPADD(x[i], 0x4E);
#pragma unroll
  for (int i = 0; i < 16; i++) DPPADD(x[i], 0x141);
#pragma unroll
  for (int i = 0; i < 16; i++) DPPADD(x[i], 0x140);
}

// ---------------- fused fp32 -> bf16 cast for up to 8 tensors ----------------
struct CastArgs {
  const float* s[8];
  uint16_t* d[8];
  int n[8];
};
__global__ __launch_bounds__(256) void cast_multi(CastArgs a) {
  int i = blockIdx.y;
  int base = (blockIdx.x * 256 + threadIdx.x) * 8;
  if (base >= a.n[i]) return;
  const float4* sp = (const float4*)(a.s[i] + base);
  float4 x0 = sp[0], x1 = sp[1];
  uint32_t p0 = (uint32_t)f2bf(x0.x) | ((uint32_t)f2bf(x0.y) << 16);
  uint32_t p1 = (uint32_t)f2bf(x0.z) | ((uint32_t)f2bf(x0.w) << 16);
  uint32_t p2 = (uint32_t)f2bf(x1.x) | ((uint32_t)f2bf(x1.y) << 16);
  uint32_t p3 = (uint32_t)f2bf(x1.z) | ((uint32_t)f2bf(x1.w) << 16);
  uint4 v = {p0, p1, p2, p3};
  *(uint4*)(a.d[i] + base) = v;
}

// ---------------- bf16 MFMA GEMM: C[M,N] = A[M,K] @ B[N,K]^T ----------------
struct GJobs {
  const uint16_t* A[5];
  const uint16_t* B[5];
  void* C[5];
  int N[5];
  int outbf[5];
};
__global__ __launch_bounds__(256) void gemm_mfma(GJobs j, int K) {
  const int z = blockIdx.z;
  const int N = j.N[z];
  const int n0 = blockIdx.x * 128;
  if (n0 >= N) return;
  __shared__ uint16_t Asb[128 * 32];
  __shared__ uint16_t Bsb[128 * 32];
  const uint16_t* __restrict__ A = j.A[z];
  const uint16_t* __restrict__ B = j.B[z];
  const int tid = threadIdx.x;
  const int w = tid >> 6, lane = tid & 63;
  const int m0 = blockIdx.y * 128;
  const int mw = (w & 1) * 64, nw = (w >> 1) * 64;
  const int c0 = tid, c1 = 256 + tid;
  const int r0 = c0 >> 2, cl0 = (c0 & 3) ^ ((r0 >> 2) & 3);
  const int r1 = c1 >> 2, cl1 = (c1 & 3) ^ ((r1 >> 2) & 3);
  const uint16_t* gA0 = A + (size_t)(m0 + r0) * K + cl0 * 8;
  const uint16_t* gA1 = A + (size_t)(m0 + r1) * K + cl1 * 8;
  const uint16_t* gB0 = B + (size_t)(n0 + r0) * K + cl0 * 8;
  const uint16_t* gB1 = B + (size_t)(n0 + r1) * K + cl1 * 8;
  uint16_t* lA0 = Asb + w * 512;
  uint16_t* lA1 = Asb + 2048 + w * 512;
  uint16_t* lB0 = Bsb + w * 512;
  uint16_t* lB1 = Bsb + 2048 + w * 512;

  const int l15 = lane & 15, q = lane >> 4;
  const int ccq = q ^ ((l15 >> 2) & 3);

  f32x4 acc[4][4] = {};
  for (int k0 = 0; k0 < K; k0 += 32) {
    glds16(gA0 + k0, lA0);
    glds16(gA1 + k0, lA1);
    glds16(gB0 + k0, lB0);
    glds16(gB1 + k0, lB1);
    __syncthreads();
    bf16x8 af[4], bfr[4];
#pragma unroll
    for (int i = 0; i < 4; i++)
      af[i] = *(const bf16x8*)&Asb[(mw + i * 16 + l15) * 32 + ccq * 8];
#pragma unroll
    for (int jx = 0; jx < 4; jx++)
      bfr[jx] = *(const bf16x8*)&Bsb[(nw + jx * 16 + l15) * 32 + ccq * 8];
#pragma unroll
    for (int i = 0; i < 4; i++)
#pragma unroll
      for (int jx = 0; jx < 4; jx++)
        acc[i][jx] = __builtin_amdgcn_mfma_f32_16x16x32_bf16(af[i], bfr[jx],
                                                             acc[i][jx], 0, 0, 0);
    __syncthreads();
  }
  const int obf = j.outbf[z];
#pragma unroll
  for (int i = 0; i < 4; i++) {
#pragma unroll
    for (int jx = 0; jx < 4; jx++) {
      int n = n0 + nw + jx * 16 + l15;
#pragma unroll
      for (int r = 0; r < 4; r++) {
        int m = m0 + mw + i * 16 + q * 4 + r;
        if (obf)
          ((uint16_t*)j.C[z])[(size_t)m * N + n] = f2bf(acc[i][jx][r]);
        else
          ((float*)j.C[z])[(size_t)m * N + n] = acc[i][jx][r];
      }
    }
  }
}

// ---------------- fp32 GEMM (numerically-sensitive g-path + Wb) -----
__global__ __launch_bounds__(256) void gemm_abt(
    const float* __restrict__ A, const float* __restrict__ B,
    float* __restrict__ C, int M, int N, int Kd) {
  __shared__ float As[16][68];
  __shared__ float Bs[16][68];
  const int tid = threadIdx.x;
  const int m0 = blockIdx.y * 64, n0 = blockIdx.x * 64;
  const int tx = tid & 15, ty = tid >> 4;
  const int lk = tid & 15, lr = tid >> 4;
  float acc[4][4] = {};
  for (int k0 = 0; k0 < Kd; k0 += 16) {
#pragma unroll
    for (int i = 0; i < 4; i++) {
      int m = m0 + lr + 16 * i;
      As[lk][lr + 16 * i] = (m < M) ? A[(size_t)m * Kd + k0 + lk] : 0.f;
      int n = n0 + lr + 16 * i;
      Bs[lk][lr + 16 * i] = (n < N) ? B[(size_t)n * Kd + k0 + lk] : 0.f;
    }
    __syncthreads();
#pragma unroll
    for (int kk = 0; kk < 16; kk++) {
      float4 a4 = *(const float4*)&As[kk][ty * 4];
      float4 b4 = *(const float4*)&Bs[kk][tx * 4];
      float av[4] = {a4.x, a4.y, a4.z, a4.w};
      float bv[4] = {b4.x, b4.y, b4.z, b4.w};
#pragma unroll
      for (int i = 0; i < 4; i++)
#pragma unroll
        for (int jx = 0; jx < 4; jx++) acc[i][jx] = fmaf(av[i], bv[jx], acc[i][jx]);
    }
    __syncthreads();
  }
#pragma unroll
  for (int i = 0; i < 4; i++) {
    int m = m0 + ty * 4 + i;
    if (m >= M) continue;
#pragma unroll
    for (int jx = 0; jx < 4; jx++) {
      int n = n0 + tx * 4 + jx;
      if (n < N) C[(size_t)m * N + n] = acc[i][jx];
    }
  }
}

// -------- depthwise causal conv(K=4) + silu for q,k,v and ve; mix v ----------
__global__ __launch_bounds__(256) void conv_silu_mix(
    const float* __restrict__ qp, const float* __restrict__ kp,
    const float* __restrict__ vp, const float* __restrict__ vep,
    const float* __restrict__ wq, const float* __restrict__ wk,
    const float* __restrict__ wv, const float* __restrict__ lam,
    float* __restrict__ qc, float* __restrict__ kc, float* __restrict__ vmx) {
  int idx = blockIdx.x * 256 + threadIdx.x;
  if (idx >= S_LEN * KD_) return;
  int s = idx >> 10, d = idx & 1023;
  float aq = 0.f, ak = 0.f, av = 0.f, ae = 0.f;
#pragma unroll
  for (int i = 0; i < KCONV; i++) {
    int ss = s - (KCONV - 1) + i;
    if (ss < 0) continue;
    size_t off = (size_t)ss * KD_ + d;
    aq = fmaf(qp[off], wq[d * KCONV + i], aq);
    ak = fmaf(kp[off], wk[d * KCONV + i], ak);
    av = fmaf(vp[off], wv[d * KCONV + i], av);
    ae = fmaf(vep[off], wv[d * KCONV + i], ae);
  }
  qc[idx] = aq / (1.f + expf(-aq));
  kc[idx] = ak / (1.f + expf(-ak));
  float sv = av / (1.f + expf(-av));
  float se = ae / (1.f + expf(-ae));
  vmx[idx] = lam[0] * sv + lam[1] * se;
}

// ------ g = -exp(A_log)*softplus(graw+dt_bias), in place (RAW g now) ------
__global__ __launch_bounds__(256) void g_only(
    float* __restrict__ graw, const float* __restrict__ dt_bias,
    const float* __restrict__ A_log) {
  int idx = blockIdx.x * 256 + threadIdx.x;
  if (idx >= S_LEN * KD_) return;
  int c = idx & 1023;
  float xv = graw[idx] + dt_bias[c];
  float sp = (xv > 20.f) ? xv : log1pf(expf(xv));
  graw[idx] = -expf(A_log[c >> 7]) * sp;
}

// ---------------- KDA window precompute (fully parallel, per (w,h)) ----------
// thread (t = tid>>4, kg = tid&15): owns step t, channels d in [kg*8, kg*8+8).
// Outputs (scan half-split layout, element (t,d): t*128 + (d>>3 part)):
//   khat = P_t .* kn_t, qhat = P_t .* qn_t, kchk = exp(G15-G_t) .* kn_t,
//   Mt[j][t2] = M_{t2,j} = k_t2.(exp(G_t2-G_j).*k_j), N[t][j] = q_t.(...k_j),
//   Pbar = exp(G15). All exponents <= 0 (g<=0, t>=j) -> safe.
__global__ __launch_bounds__(256, 2) void kda_pre(
    const float* __restrict__ qc, const float* __restrict__ kc,
    const float* __restrict__ g, float* __restrict__ pre) {
  __shared__ float kls[16 * 128];
  __shared__ float gls[16 * 128];
  __shared__ float Gls[16 * 128];
  const int w = blockIdx.x >> 3, h = blockIdx.x & 7;
  const int tid = threadIdx.x;
  const int t = tid >> 4, kg = tid & 15;
  size_t rowoff = (size_t)(w * 16 + t) * KD_ + h * DK_ + kg * 8;
  float4 kv0 = *(const float4*)(kc + rowoff), kv1 = *(const float4*)(kc + rowoff + 4);
  float4 qv0 = *(const float4*)(qc + rowoff), qv1 = *(const float4*)(qc + rowoff + 4);
  float4 gv0 = *(const float4*)(g + rowoff), gv1 = *(const float4*)(g + rowoff + 4);
  // fused l2norm (over 16 kg lanes = full 128 channels of this step)
  float sk = dot4(kv0, kv0) + dot4(kv1, kv1);
  float sq = dot4(qv0, qv0) + dot4(qv1, qv1);
  row16_sum2(sk, sq);
  float rkn = rsqrtf(sk + 1e-6f);
  float rqn = rsqrtf(sq + 1e-6f) * 0.08838834764831845f;  // * DK^-0.5
  kv0 = f4s(kv0, rkn); kv1 = f4s(kv1, rkn);
  qv0 = f4s(qv0, rqn); qv1 = f4s(qv1, rqn);
  *(float4*)&kls[t * 128 + kg * 4] = kv0;
  *(float4*)&kls[t * 128 + 64 + kg * 4] = kv1;
  *(float4*)&gls[t * 128 + kg * 4] = gv0;
  *(float4*)&gls[t * 128 + 64 + kg * 4] = gv1;
  __syncthreads();
  // inclusive cumsum G_t and full sum G15 (own 8 channels)
  float4 Ga = {0, 0, 0, 0}, Gb = {0, 0, 0, 0};
  float4 Gfa = {0, 0, 0, 0}, Gfb = {0, 0, 0, 0};
#pragma unroll
  for (int j = 0; j < 16; j++) {
    float4 g0 = *(const float4*)&gls[j * 128 + kg * 4];
    float4 g1 = *(const float4*)&gls[j * 128 + 64 + kg * 4];
    Gfa = f4add(Gfa, g0); Gfb = f4add(Gfb, g1);
    if (j <= t) { Ga = f4add(Ga, g0); Gb = f4add(Gb, g1); }
  }
  *(float4*)&Gls[t * 128 + kg * 4] = Ga;
  *(float4*)&Gls[t * 128 + 64 + kg * 4] = Gb;
  __syncthreads();
  const size_t base = (size_t)blockIdx.x * PRE_STRIDE;
  float4 Pa = f4exp(Ga), Pb = f4exp(Gb);
  *(float4*)(pre + base + t * 128 + kg * 4) = f4mul(kv0, Pa);
  *(float4*)(pre + base + t * 128 + 64 + kg * 4) = f4mul(kv1, Pb);
  *(float4*)(pre + base + 2048 + t * 128 + kg * 4) = f4mul(qv0, Pa);
  *(float4*)(pre + base + 2048 + t * 128 + 64 + kg * 4) = f4mul(qv1, Pb);
  float4 ea = f4exp(f4sub(Gfa, Ga)), eb = f4exp(f4sub(Gfb, Gb));
  *(float4*)(pre + base + 4096 + t * 128 + kg * 4) = f4mul(kv0, ea);
  *(float4*)(pre + base + 4096 + t * 128 + 64 + kg * 4) = f4mul(kv1, eb);
  if (t == 15) {
    *(float4*)(pre + base + 6656 + kg * 4) = Pa;
    *(float4*)(pre + base + 6656 + 64 + kg * 4) = Pb;
  }
  // M/N partials over own 8 channels, j = 0..15 (j>t zeroed)
  float mp[16], np[16];
#pragma unroll
  for (int j = 0; j < 16; j++) {
    float4 kj0 = *(const float4*)&kls[j * 128 + kg * 4];
    float4 kj1 = *(const float4*)&kls[j * 128 + 64 + kg * 4];
    float4 Gj0 = *(const float4*)&Gls[j * 128 + kg * 4];
    float4 Gj1 = *(const float4*)&Gls[j * 128 + 64 + kg * 4];
    float4 e0 = f4exp(f4sub(Ga, Gj0));
    float4 e1 = f4exp(f4sub(Gb, Gj1));
    float4 p0 = f4mul(kj0, e0), p1 = f4mul(kj1, e1);
    float m = dot4(kv0, p0) + dot4(kv1, p1);
    float n = dot4(qv0, p0) + dot4(qv1, p1);
    mp[j] = (j <= t) ? m : 0.f;
    np[j] = (j <= t) ? n : 0.f;
  }
  row16_arr16(mp);
  row16_arr16(np);
#pragma unroll
  for (int j = 0; j < 16; j++) {
    if (kg == j) {
      pre[base + 6144 + j * 16 + t] = mp[j];  // Mt[j][t] = M_{t,j} (transposed)
      pre[base + 6400 + t * 16 + j] = np[j];  // N[t][j]
    }
  }
}

// ---------------- KDA scan over windows (serial chain = fwd-sub only) --------
// block: h = bx&7 (same-head blocks share an XCD's L2), vg = bx>>3.
// lane: kg = lane&15 owns channels [kg*8,kg*8+8); col = wave*4 + (lane>>4).
__global__ __launch_bounds__(256, 1) void kda_scan(
    const float* __restrict__ pre, const float* __restrict__ vm,
    const float* __restrict__ bpre, float* __restrict__ o) {
  __shared__ float Pls[2][6144];      // khat | qhat | kchk
  __shared__ float Mts[2][16 * 20];   // padded rows
  __shared__ float Nls[2][16 * 20];
  __shared__ float Pbar[2][128];
  __shared__ float Vt[2][256];
  __shared__ float Bt[2][16];
  const int h = blockIdx.x & 7, vg = blockIdx.x >> 3;
  const int tid = threadIdx.x;
  const int lane = tid & 63;
  const int kg = lane & 15;
  const int col = (tid >> 6) * 4 + (lane >> 4);

  float4 rp[6], rmn, rpb, rv;
  float rb;
  auto load_g = [&](int w) {
    size_t base = (size_t)(w * 8 + h) * PRE_STRIDE;
#pragma unroll
    for (int i = 0; i < 6; i++)
      rp[i] = *(const float4*)(pre + base + (size_t)(i * 256 + tid) * 4);
    if (tid < 128) rmn = *(const float4*)(pre + base + 6144 + tid * 4);
    if (tid < 32) rpb = *(const float4*)(pre + base + 6656 + tid * 4);
    if (tid < 64)
      rv = *(const float4*)(vm + (size_t)(w * 16 + (tid >> 2)) * KD_ + h * DV_ +
                            vg * 16 + (tid & 3) * 4);
    if (tid < 16) rb = bpre[(size_t)(w * 16 + tid) * NH + h];
  };
  auto commit = [&](int b) {
#pragma unroll
    for (int i = 0; i < 6; i++)
      *(float4*)&Pls[b][(i * 256 + tid) * 4] = rp[i];
    if (tid < 64)
      *(float4*)&Mts[b][(tid >> 2) * 20 + (tid & 3) * 4] = rmn;
    else if (tid < 128)
      *(float4*)&Nls[b][((tid - 64) >> 2) * 20 + (tid & 3) * 4] = rmn;
    if (tid < 32) *(float4*)&Pbar[b][tid * 4] = rpb;
    if (tid < 64) *(float4*)&Vt[b][(tid >> 2) * 16 + (tid & 3) * 4] = rv;
    if (tid < 16) Bt[b][tid] = 1.f / (1.f + expf(-rb));
  };

  load_g(0);
  commit(0);
  __syncthreads();

  float4 sA = {0, 0, 0, 0}, sB = {0, 0, 0, 0};  // S0 slice [8 ch][this col]
  for (int w = 0; w < NWIN; w++) {
    const int cur = w & 1;
    const bool more = (w + 1 < NWIN);
    if (more) load_g(w + 1);
    const float* Pc = Pls[cur];
    // ---- Phase A: a = Khat.S0, b = Qhat.S0 (batched dots + butterflies) ----
    float aa[16], bb[16];
#pragma unroll
    for (int t = 0; t < 16; t++) {
      float4 ka = *(const float4*)&Pc[t * 128 + kg * 4];
      float4 kb = *(const float4*)&Pc[t * 128 + 64 + kg * 4];
      float4 qa = *(const float4*)&Pc[2048 + t * 128 + kg * 4];
      float4 qb = *(const float4*)&Pc[2048 + t * 128 + 64 + kg * 4];
      aa[t] = dot4(ka, sA) + dot4(kb, sB);
      bb[t] = dot4(qa, sA) + dot4(qb, sB);
    }
    row16_arr16(aa);
    row16_arr16(bb);
    // ---- Phase B: forward substitution (tiny serial chain) ----
    float vv[16], bts[16];
#pragma unroll
    for (int t = 0; t < 16; t++) {
      vv[t] = Vt[cur][t * 16 + col];
      bts[t] = Bt[cur][t];
    }
    float acc[16], vnw[16];
#pragma unroll
    for (int t = 0; t < 16; t++) acc[t] = 0.f;
#pragma unroll
    for (int t = 0; t < 16; t++) {
      vnw[t] = (vv[t] - aa[t] - acc[t]) * bts[t];
      float mr[16];
      *(float4*)&mr[0] = *(const float4*)&Mts[cur][t * 20 + 0];
      *(float4*)&mr[4] = *(const float4*)&Mts[cur][t * 20 + 4];
      *(float4*)&mr[8] = *(const float4*)&Mts[cur][t * 20 + 8];
      *(float4*)&mr[12] = *(const float4*)&Mts[cur][t * 20 + 12];
#pragma unroll
      for (int t2 = t + 1; t2 < 16; t2++)
        acc[t2] = fmaf(mr[t2], vnw[t], acc[t2]);
    }
    // ---- Phase C: o_t = b_t + sum_{j<=t} N_tj vnw_j ----
#pragma unroll
    for (int t = 0; t < 16; t++) {
      float nr[16];
      *(float4*)&nr[0] = *(const float4*)&Nls[cur][t * 20 + 0];
      *(float4*)&nr[4] = *(const float4*)&Nls[cur][t * 20 + 4];
      *(float4*)&nr[8] = *(const float4*)&Nls[cur][t * 20 + 8];
      *(float4*)&nr[12] = *(const float4*)&Nls[cur][t * 20 + 12];
      float ot = bb[t];
#pragma unroll
      for (int jj = 0; jj <= t; jj++) ot = fmaf(nr[jj], vnw[jj], ot);
      if (kg == 0)
        o[(size_t)(w * 16 + t) * KD_ + h * DK_ + vg * 16 + col] = ot;
    }
    // ---- Phase D: S0 = Pbar.*S0 + sum_j kchk_j * vnw_j ----
    {
      float4 p0 = *(const float4*)&Pbar[cur][kg * 4];
      float4 p1 = *(const float4*)&Pbar[cur][64 + kg * 4];
      sA = f4mul(sA, p0);
      sB = f4mul(sB, p1);
#pragma unroll
      for (int jj = 0; jj < 16; jj++) {
        float4 c0 = *(const float4*)&Pc[4096 + jj * 128 + kg * 4];
        float4 c1 = *(const float4*)&Pc[4096 + jj * 128 + 64 + kg * 4];
        sA = f4fma(c0, vnw[jj], sA);
        sB = f4fma(c1, vnw[jj], sB);
      }
    }
    if (more) commit(cur ^ 1);
    __syncthreads();
  }
}

// ---- FusedRMSNormGated: gate = sigmoid(g2raw + bg2) fused; bf16 out ----
__global__ __launch_bounds__(64) void gated_rmsnorm(
    const float* __restrict__ o, const float* __restrict__ g2raw,
    const float* __restrict__ bg2, const float* __restrict__ wn,
    uint16_t* __restrict__ ob) {
  size_t base = (size_t)blockIdx.x * DV_;
  int t = threadIdx.x;
  float a = o[base + t], b = o[base + t + 64];
  float ss = a * a + b * b;
#pragma unroll
  for (int off = 32; off > 0; off >>= 1) ss += __shfl_xor(ss, off);
  float r = rsqrtf(ss * (1.f / 128.f) + 1e-5f);
  int c0 = (int)((base + t) & 1023), c1 = (int)((base + t + 64) & 1023);
  float ga = 1.f / (1.f + expf(-(g2raw[base + t] + bg2[c0])));
  float gb = 1.f / (1.f + expf(-(g2raw[base + t + 64] + bg2[c1])));
  ob[base + t] = f2bf(a * r * wn[t] * ga);
  ob[base + t + 64] = f2bf(b * r * wn[t + 64] * gb);
}

extern "C" void kernel_launch(void* const* d_in, const int* in_sizes, int n_in,
                              void* d_out, int out_size, void* d_ws, size_t ws_size,
                              hipStream_t stream) {
  const float* x = (const float*)d_in[0];
  const float* ve = (const float*)d_in[1];
  const float* lam = (const float*)d_in[2];
  const float* Wq = (const float*)d_in[3];
  const float* Wk = (const float*)d_in[4];
  const float* Wv = (const float*)d_in[5];
  const float* Wo = (const float*)d_in[6];
  const float* wq_conv = (const float*)d_in[7];
  const float* wk_conv = (const float*)d_in[8];
  const float* wv_conv = (const float*)d_in[9];
  const float* Wf1 = (const float*)d_in[10];
  const float* Wf2 = (const float*)d_in[11];
  const float* Wb = (const float*)d_in[12];
  const float* A_log = (const float*)d_in[13];
  const float* dt_bias = (const float*)d_in[14];
  const float* Wg1 = (const float*)d_in[15];
  const float* Wg2 = (const float*)d_in[16];
  const float* bg2 = (const float*)d_in[17];
  const float* w_norm = (const float*)d_in[18];
  float* out = (float*)d_out;

  float* ws = (float*)d_ws;
  const size_t SZ = (size_t)S_LEN * KD_;  // 2M floats
  float* q_pre = ws;
  float* k_pre = ws + SZ;
  float* v_pre = ws + 2 * SZ;
  float* ve_pre = ws + 3 * SZ;
  float* q_c = ws + 4 * SZ;
  float* k_c = ws + 5 * SZ;
  float* v_mix = ws + 6 * SZ;
  float* f1 = ve_pre;                              // [S,128] after conv
  float* bpre = ve_pre + 2 * (size_t)S_LEN * DV_;  // [S,8] raw (sigmoid in scan)
  float* graw = q_pre;                             // -> raw g in place
  float* g2raw = k_pre;                            // raw gate pre-activation
  float* o_buf = v_pre;
  uint16_t* bws = (uint16_t*)(ws + 7 * SZ);
  uint16_t* xb = bws;
  uint16_t* veb = xb + SZ;
  uint16_t* Wqb = veb + SZ;
  uint16_t* Wkb = Wqb + (size_t)KD_ * DMODEL;
  uint16_t* Wvb = Wkb + (size_t)KD_ * DMODEL;
  uint16_t* Wob = Wvb + (size_t)KD_ * DMODEL;
  uint16_t* Wg1b = Wob + (size_t)DMODEL * KD_;
  uint16_t* Wg2b = Wg1b + (size_t)DV_ * DMODEL;
  uint16_t* g1b = Wg2b + (size_t)KD_ * DV_;        // [S,128] bf16
  uint16_t* ob = g1b + (size_t)S_LEN * DV_;        // [S,1024] bf16
  float* pre_buf = ws + (size_t)20 * 1024 * 1024;  // 1024 * 6784 floats (~27.8 MB)

  dim3 blk(256);
  int ew_blocks = (S_LEN * KD_ + 255) / 256;

  CastArgs ca;
  ca.s[0] = x;   ca.d[0] = xb;   ca.n[0] = S_LEN * DMODEL;
  ca.s[1] = ve;  ca.d[1] = veb;  ca.n[1] = S_LEN * DMODEL;
  ca.s[2] = Wq;  ca.d[2] = Wqb;  ca.n[2] = KD_ * DMODEL;
  ca.s[3] = Wk;  ca.d[3] = Wkb;  ca.n[3] = KD_ * DMODEL;
  ca.s[4] = Wv;  ca.d[4] = Wvb;  ca.n[4] = KD_ * DMODEL;
  ca.s[5] = Wo;  ca.d[5] = Wob;  ca.n[5] = DMODEL * KD_;
  ca.s[6] = Wg1; ca.d[6] = Wg1b; ca.n[6] = DV_ * DMODEL;
  ca.s[7] = Wg2; ca.d[7] = Wg2b; ca.n[7] = KD_ * DV_;
  cast_multi<<<dim3(1024, 8), blk, 0, stream>>>(ca);

  GJobs jq;
  jq.A[0] = xb;  jq.B[0] = Wqb;  jq.C[0] = q_pre;  jq.N[0] = KD_; jq.outbf[0] = 0;
  jq.A[1] = xb;  jq.B[1] = Wkb;  jq.C[1] = k_pre;  jq.N[1] = KD_; jq.outbf[1] = 0;
  jq.A[2] = xb;  jq.B[2] = Wvb;  jq.C[2] = v_pre;  jq.N[2] = KD_; jq.outbf[2] = 0;
  jq.A[3] = veb; jq.B[3] = Wvb;  jq.C[3] = ve_pre; jq.N[3] = KD_; jq.outbf[3] = 0;
  jq.A[4] = xb;  jq.B[4] = Wg1b; jq.C[4] = g1b;    jq.N[4] = DV_; jq.outbf[4] = 1;
  gemm_mfma<<<dim3(8, 16, 5), blk, 0, stream>>>(jq, DMODEL);

  conv_silu_mix<<<ew_blocks, blk, 0, stream>>>(q_pre, k_pre, v_pre, ve_pre,
                                               wq_conv, wk_conv, wv_conv, lam,
                                               q_c, k_c, v_mix);

  gemm_abt<<<dim3(2, 32), blk, 0, stream>>>(x, Wf1, f1, S_LEN, DV_, DMODEL);
  gemm_abt<<<dim3(1, 32), blk, 0, stream>>>(x, Wb, bpre, S_LEN, NH, DMODEL);
  gemm_abt<<<dim3(16, 32), blk, 0, stream>>>(f1, Wf2, graw, S_LEN, KD_, DV_);
  g_only<<<ew_blocks, blk, 0, stream>>>(graw, dt_bias, A_log);

  kda_pre<<<dim3(NWIN * 8), blk, 0, stream>>>(q_c, k_c, graw, pre_buf);
  kda_scan<<<dim3(64), blk, 0, stream>>>(pre_buf, v_mix, bpre, o_buf);

  GJobs jg2;
  jg2.A[0] = g1b; jg2.B[0] = Wg2b; jg2.C[0] = g2raw; jg2.N[0] = KD_; jg2.outbf[0] = 0;
  gemm_mfma<<<dim3(8, 16, 1), blk, 0, stream>>>(jg2, DV_);

  gated_rmsnorm<<<dim3(S_LEN * NH), dim3(64), 0, stream>>>(o_buf, g2raw, bg2,
                                                           w_norm, ob);

  GJobs jo;
  jo.A[0] = ob; jo.B[0] = Wob; jo.C[0] = out; jo.N[0] = DMODEL; jo.outbf[0] = 0;
  gemm_mfma<<<dim3(8, 16, 1), blk, 0, stream>>>(jo, KD_);
}

// Round 6
// 983.121 us; speedup vs baseline: 1.1147x; 1.1147x over previous
//
#include <hip/hip_runtime.h>
#include <math.h>
#include <stdint.h>

#define S_LEN 2048
#define DMODEL 1024
#define NH 8
#define DK_ 128
#define DV_ 128
#define KD_ 1024
#define KCONV 4
#define NWIN 128
#define PREB_STRIDE 8192  // uint16 per (w,h): TKh 2048 | Qhat 2048 | Kchk 2048 | Tvt 2048
#define PREF_STRIDE 384   // float  per (w,h): N 256 | Pbar 128

typedef short bf16x8 __attribute__((ext_vector_type(8)));
typedef float f32x4 __attribute__((ext_vector_type(4)));

__device__ __forceinline__ uint16_t f2bf(float f) {  // RNE
  uint32_t u = __float_as_uint(f);
  u += 0x7FFF + ((u >> 16) & 1);
  return (uint16_t)(u >> 16);
}

__device__ __forceinline__ void glds16(const uint16_t* g, uint16_t* l) {
  __builtin_amdgcn_global_load_lds(
      (const __attribute__((address_space(1))) void*)g,
      (__attribute__((address_space(3))) void*)l, 16, 0, 0);
}

__device__ __forceinline__ float dot4(float4 a, float4 b) {
  return fmaf(a.w, b.w, fmaf(a.z, b.z, fmaf(a.y, b.y, a.x * b.x)));
}
__device__ __forceinline__ float4 f4add(float4 a, float4 b) {
  float4 r; r.x = a.x + b.x; r.y = a.y + b.y; r.z = a.z + b.z; r.w = a.w + b.w; return r;
}
__device__ __forceinline__ float4 f4sub(float4 a, float4 b) {
  float4 r; r.x = a.x - b.x; r.y = a.y - b.y; r.z = a.z - b.z; r.w = a.w - b.w; return r;
}
__device__ __forceinline__ float4 f4mul(float4 a, float4 b) {
  float4 r; r.x = a.x * b.x; r.y = a.y * b.y; r.z = a.z * b.z; r.w = a.w * b.w; return r;
}
__device__ __forceinline__ float4 f4s(float4 a, float s) {
  float4 r; r.x = a.x * s; r.y = a.y * s; r.z = a.z * s; r.w = a.w * s; return r;
}
__device__ __forceinline__ float4 f4fma(float4 a, float s, float4 c) {
  float4 r; r.x = fmaf(a.x, s, c.x); r.y = fmaf(a.y, s, c.y);
  r.z = fmaf(a.z, s, c.z); r.w = fmaf(a.w, s, c.w); return r;
}
__device__ __forceinline__ float4 f4exp(float4 a) {
  float4 r; r.x = expf(a.x); r.y = expf(a.y); r.z = expf(a.z); r.w = expf(a.w); return r;
}
__device__ __forceinline__ uint4 pack8(float4 a, float4 b) {  // elem order a.x..b.w
  uint4 r;
  r.x = (uint32_t)f2bf(a.x) | ((uint32_t)f2bf(a.y) << 16);
  r.y = (uint32_t)f2bf(a.z) | ((uint32_t)f2bf(a.w) << 16);
  r.z = (uint32_t)f2bf(b.x) | ((uint32_t)f2bf(b.y) << 16);
  r.w = (uint32_t)f2bf(b.z) | ((uint32_t)f2bf(b.w) << 16);
  return r;
}
__device__ __forceinline__ void unp8(uint4 u, float* f) {
  f[0] = __uint_as_float(u.x << 16); f[1] = __uint_as_float(u.x & 0xFFFF0000u);
  f[2] = __uint_as_float(u.y << 16); f[3] = __uint_as_float(u.y & 0xFFFF0000u);
  f[4] = __uint_as_float(u.z << 16); f[5] = __uint_as_float(u.z & 0xFFFF0000u);
  f[6] = __uint_as_float(u.w << 16); f[7] = __uint_as_float(u.w & 0xFFFF0000u);
}

#define DPPADD(x, ctrl) \
  x += __int_as_float(__builtin_amdgcn_update_dpp(0, __float_as_int(x), ctrl, 0xF, 0xF, true))

__device__ __forceinline__ void row16_sum2(float& a, float& b) {
  DPPADD(a, 0xB1); DPPADD(b, 0xB1);
  DPPADD(a, 0x4E); DPPADD(b, 0x4E);
  DPPADD(a, 0x141); DPPADD(b, 0x141);
  DPPADD(a, 0x140); DPPADD(b, 0x140);
}
__device__ __forceinline__ void row16_arr16(float* x) {
#pragma unroll
  for (int i = 0; i < 16; i++) DPPADD(x[i], 0xB1);
#pragma unroll
  for (int i = 0; i < 16; i++) DPPADD(x[i], 0x4E);
#pragma unroll
  for (int i = 0; i < 16; i++) DPPADD(x[i], 0x141);
#pragma unroll
  for (int i = 0; i < 16; i++) DPPADD(x[i], 0x140);
}

// ---------------- fused fp32 -> bf16 cast for up to 8 tensors ----------------
struct CastArgs {
  const float* s[8];
  uint16_t* d[8];
  int n[8];
};
__global__ __launch_bounds__(256) void cast_multi(CastArgs a) {
  int i = blockIdx.y;
  int base = (blockIdx.x * 256 + threadIdx.x) * 8;
  if (base >= a.n[i]) return;
  const float4* sp = (const float4*)(a.s[i] + base);
  float4 x0 = sp[0], x1 = sp[1];
  uint4 v = pack8(x0, x1);
  *(uint4*)(a.d[i] + base) = v;
}

// ---------------- bf16 MFMA GEMM: C[M,N] = A[M,K] @ B[N,K]^T ----------------
struct GJobs {
  const uint16_t* A[5];
  const uint16_t* B[5];
  void* C[5];
  int N[5];
  int outbf[5];
};
__global__ __launch_bounds__(256) void gemm_mfma(GJobs j, int K) {
  const int z = blockIdx.z;
  const int N = j.N[z];
  const int n0 = blockIdx.x * 128;
  if (n0 >= N) return;
  __shared__ uint16_t Asb[128 * 32];
  __shared__ uint16_t Bsb[128 * 32];
  const uint16_t* __restrict__ A = j.A[z];
  const uint16_t* __restrict__ B = j.B[z];
  const int tid = threadIdx.x;
  const int w = tid >> 6, lane = tid & 63;
  const int m0 = blockIdx.y * 128;
  const int mw = (w & 1) * 64, nw = (w >> 1) * 64;
  const int c0 = tid, c1 = 256 + tid;
  const int r0 = c0 >> 2, cl0 = (c0 & 3) ^ ((r0 >> 2) & 3);
  const int r1 = c1 >> 2, cl1 = (c1 & 3) ^ ((r1 >> 2) & 3);
  const uint16_t* gA0 = A + (size_t)(m0 + r0) * K + cl0 * 8;
  const uint16_t* gA1 = A + (size_t)(m0 + r1) * K + cl1 * 8;
  const uint16_t* gB0 = B + (size_t)(n0 + r0) * K + cl0 * 8;
  const uint16_t* gB1 = B + (size_t)(n0 + r1) * K + cl1 * 8;
  uint16_t* lA0 = Asb + w * 512;
  uint16_t* lA1 = Asb + 2048 + w * 512;
  uint16_t* lB0 = Bsb + w * 512;
  uint16_t* lB1 = Bsb + 2048 + w * 512;

  const int l15 = lane & 15, q = lane >> 4;
  const int ccq = q ^ ((l15 >> 2) & 3);

  f32x4 acc[4][4] = {};
  for (int k0 = 0; k0 < K; k0 += 32) {
    glds16(gA0 + k0, lA0);
    glds16(gA1 + k0, lA1);
    glds16(gB0 + k0, lB0);
    glds16(gB1 + k0, lB1);
    __syncthreads();
    bf16x8 af[4], bfr[4];
#pragma unroll
    for (int i = 0; i < 4; i++)
      af[i] = *(const bf16x8*)&Asb[(mw + i * 16 + l15) * 32 + ccq * 8];
#pragma unroll
    for (int jx = 0; jx < 4; jx++)
      bfr[jx] = *(const bf16x8*)&Bsb[(nw + jx * 16 + l15) * 32 + ccq * 8];
#pragma unroll
    for (int i = 0; i < 4; i++)
#pragma unroll
      for (int jx = 0; jx < 4; jx++)
        acc[i][jx] = __builtin_amdgcn_mfma_f32_16x16x32_bf16(af[i], bfr[jx],
                                                             acc[i][jx], 0, 0, 0);
    __syncthreads();
  }
  const int obf = j.outbf[z];
#pragma unroll
  for (int i = 0; i < 4; i++) {
#pragma unroll
    for (int jx = 0; jx < 4; jx++) {
      int n = n0 + nw + jx * 16 + l15;
#pragma unroll
      for (int r = 0; r < 4; r++) {
        int m = m0 + mw + i * 16 + q * 4 + r;
        if (obf)
          ((uint16_t*)j.C[z])[(size_t)m * N + n] = f2bf(acc[i][jx][r]);
        else
          ((float*)j.C[z])[(size_t)m * N + n] = acc[i][jx][r];
      }
    }
  }
}

// ---------------- fp32 GEMM (numerically-sensitive g-path + Wb) -----
__global__ __launch_bounds__(256) void gemm_abt(
    const float* __restrict__ A, const float* __restrict__ B,
    float* __restrict__ C, int M, int N, int Kd) {
  __shared__ float As[16][68];
  __shared__ float Bs[16][68];
  const int tid = threadIdx.x;
  const int m0 = blockIdx.y * 64, n0 = blockIdx.x * 64;
  const int tx = tid & 15, ty = tid >> 4;
  const int lk = tid & 15, lr = tid >> 4;
  float acc[4][4] = {};
  for (int k0 = 0; k0 < Kd; k0 += 16) {
#pragma unroll
    for (int i = 0; i < 4; i++) {
      int m = m0 + lr + 16 * i;
      As[lk][lr + 16 * i] = (m < M) ? A[(size_t)m * Kd + k0 + lk] : 0.f;
      int n = n0 + lr + 16 * i;
      Bs[lk][lr + 16 * i] = (n < N) ? B[(size_t)n * Kd + k0 + lk] : 0.f;
    }
    __syncthreads();
#pragma unroll
    for (int kk = 0; kk < 16; kk++) {
      float4 a4 = *(const float4*)&As[kk][ty * 4];
      float4 b4 = *(const float4*)&Bs[kk][tx * 4];
      float av[4] = {a4.x, a4.y, a4.z, a4.w};
      float bv[4] = {b4.x, b4.y, b4.z, b4.w};
#pragma unroll
      for (int i = 0; i < 4; i++)
#pragma unroll
        for (int jx = 0; jx < 4; jx++) acc[i][jx] = fmaf(av[i], bv[jx], acc[i][jx]);
    }
    __syncthreads();
  }
#pragma unroll
  for (int i = 0; i < 4; i++) {
    int m = m0 + ty * 4 + i;
    if (m >= M) continue;
#pragma unroll
    for (int jx = 0; jx < 4; jx++) {
      int n = n0 + tx * 4 + jx;
      if (n < N) C[(size_t)m * N + n] = acc[i][jx];
    }
  }
}

// -------- depthwise causal conv(K=4) + silu for q,k,v and ve; mix v ----------
__global__ __launch_bounds__(256) void conv_silu_mix(
    const float* __restrict__ qp, const float* __restrict__ kp,
    const float* __restrict__ vp, const float* __restrict__ vep,
    const float* __restrict__ wq, const float* __restrict__ wk,
    const float* __restrict__ wv, const float* __restrict__ lam,
    float* __restrict__ qc, float* __restrict__ kc, float* __restrict__ vmx) {
  int idx = blockIdx.x * 256 + threadIdx.x;
  if (idx >= S_LEN * KD_) return;
  int s = idx >> 10, d = idx & 1023;
  float aq = 0.f, ak = 0.f, av = 0.f, ae = 0.f;
#pragma unroll
  for (int i = 0; i < KCONV; i++) {
    int ss = s - (KCONV - 1) + i;
    if (ss < 0) continue;
    size_t off = (size_t)ss * KD_ + d;
    aq = fmaf(qp[off], wq[d * KCONV + i], aq);
    ak = fmaf(kp[off], wk[d * KCONV + i], ak);
    av = fmaf(vp[off], wv[d * KCONV + i], av);
    ae = fmaf(vep[off], wv[d * KCONV + i], ae);
  }
  qc[idx] = aq / (1.f + expf(-aq));
  kc[idx] = ak / (1.f + expf(-ak));
  float sv = av / (1.f + expf(-av));
  float se = ae / (1.f + expf(-ae));
  vmx[idx] = lam[0] * sv + lam[1] * se;
}

// ------ g = -exp(A_log)*softplus(graw+dt_bias), in place (raw g) ------
__global__ __launch_bounds__(256) void g_only(
    float* __restrict__ graw, const float* __restrict__ dt_bias,
    const float* __restrict__ A_log) {
  int idx = blockIdx.x * 256 + threadIdx.x;
  if (idx >= S_LEN * KD_) return;
  int c = idx & 1023;
  float xv = graw[idx] + dt_bias[c];
  float sp = (xv > 20.f) ? xv : log1pf(expf(xv));
  graw[idx] = -expf(A_log[c >> 7]) * sp;
}

// ---------------- KDA window precompute (fully parallel, per (w,h)) ----------
// Computes, per 16-step window: TKh = T.Khat, Tv = T.v (transposed [c][t]),
// Qhat, Kchk (all bf16); N (16x16, j<=t) and Pbar=exp(G15) fp32.
// T = (I + diag(beta).M_strict)^{-1}.diag(beta). Fwd-sub runs here, fully
// parallel over 256 columns, so the scan kernel has NO serial substitution.
__global__ __launch_bounds__(256, 2) void kda_pre(
    const float* __restrict__ qc, const float* __restrict__ kc,
    const float* __restrict__ g, const float* __restrict__ vm,
    const float* __restrict__ bpre, uint16_t* __restrict__ preB,
    float* __restrict__ preF) {
  __shared__ float kls[2048], gls[2048], Gls[2048], khls[2048], vls[2048];
  __shared__ float Mb[16 * 17];
  __shared__ float bls[16];
  const int w = blockIdx.x >> 3, h = blockIdx.x & 7;
  const int tid = threadIdx.x;
  const int t = tid >> 4, kg = tid & 15;
  size_t rowoff = (size_t)(w * 16 + t) * KD_ + h * DK_ + kg * 8;
  float4 kv0 = *(const float4*)(kc + rowoff), kv1 = *(const float4*)(kc + rowoff + 4);
  float4 qv0 = *(const float4*)(qc + rowoff), qv1 = *(const float4*)(qc + rowoff + 4);
  float4 gv0 = *(const float4*)(g + rowoff), gv1 = *(const float4*)(g + rowoff + 4);
  size_t voff = (size_t)(w * 16 + t) * KD_ + h * DV_ + kg * 8;
  float4 rv0 = *(const float4*)(vm + voff), rv1 = *(const float4*)(vm + voff + 4);
  if (tid < 16) {
    float b = bpre[(size_t)(w * 16 + tid) * NH + h];
    bls[tid] = 1.f / (1.f + expf(-b));
  }
  // fused l2norm over the 16 kg lanes of this step
  float sk = dot4(kv0, kv0) + dot4(kv1, kv1);
  float sq = dot4(qv0, qv0) + dot4(qv1, qv1);
  row16_sum2(sk, sq);
  float rkn = rsqrtf(sk + 1e-6f);
  float rqn = rsqrtf(sq + 1e-6f) * 0.08838834764831845f;  // * DK^-0.5
  kv0 = f4s(kv0, rkn); kv1 = f4s(kv1, rkn);
  qv0 = f4s(qv0, rqn); qv1 = f4s(qv1, rqn);
  *(float4*)&kls[t * 128 + kg * 4] = kv0;
  *(float4*)&kls[t * 128 + 64 + kg * 4] = kv1;
  *(float4*)&gls[t * 128 + kg * 4] = gv0;
  *(float4*)&gls[t * 128 + 64 + kg * 4] = gv1;
  *(float4*)&vls[t * 128 + kg * 8] = rv0;
  *(float4*)&vls[t * 128 + kg * 8 + 4] = rv1;
  __syncthreads();
  // inclusive cumsum G_t, full sum G15 (own 8 channels)
  float4 Ga = {0, 0, 0, 0}, Gb = {0, 0, 0, 0};
  float4 Gfa = {0, 0, 0, 0}, Gfb = {0, 0, 0, 0};
#pragma unroll
  for (int j = 0; j < 16; j++) {
    float4 g0 = *(const float4*)&gls[j * 128 + kg * 4];
    float4 g1 = *(const float4*)&gls[j * 128 + 64 + kg * 4];
    Gfa = f4add(Gfa, g0); Gfb = f4add(Gfb, g1);
    if (j <= t) { Ga = f4add(Ga, g0); Gb = f4add(Gb, g1); }
  }
  *(float4*)&Gls[t * 128 + kg * 4] = Ga;
  *(float4*)&Gls[t * 128 + 64 + kg * 4] = Gb;
  const size_t b16 = (size_t)blockIdx.x * PREB_STRIDE;
  const size_t bF = (size_t)blockIdx.x * PREF_STRIDE;
  float4 Pa = f4exp(Ga), Pb = f4exp(Gb);
  float4 kh0 = f4mul(kv0, Pa), kh1 = f4mul(kv1, Pb);
  *(float4*)&khls[t * 128 + kg * 8] = kh0;
  *(float4*)&khls[t * 128 + kg * 8 + 4] = kh1;
  *(uint4*)(preB + b16 + 2048 + t * 128 + kg * 8) = pack8(f4mul(qv0, Pa), f4mul(qv1, Pb));
  float4 ea = f4exp(f4sub(Gfa, Ga)), eb = f4exp(f4sub(Gfb, Gb));
  *(uint4*)(preB + b16 + 4096 + t * 128 + kg * 8) = pack8(f4mul(kv0, ea), f4mul(kv1, eb));
  if (t == 15) {
    *(float4*)(preF + bF + 256 + kg * 8) = Pa;
    *(float4*)(preF + bF + 256 + kg * 8 + 4) = Pb;
  }
  __syncthreads();  // Gls ready (also khls/vls for later)
  // M (strict lower, beta-folded -> LDS) and N (j<=t incl diag -> preF)
  float mp[16], np[16];
#pragma unroll
  for (int j = 0; j < 16; j++) {
    float4 kj0 = *(const float4*)&kls[j * 128 + kg * 4];
    float4 kj1 = *(const float4*)&kls[j * 128 + 64 + kg * 4];
    float4 Gj0 = *(const float4*)&Gls[j * 128 + kg * 4];
    float4 Gj1 = *(const float4*)&Gls[j * 128 + 64 + kg * 4];
    float4 e0 = f4exp(f4sub(Ga, Gj0));
    float4 e1 = f4exp(f4sub(Gb, Gj1));
    float4 p0 = f4mul(kj0, e0), p1 = f4mul(kj1, e1);
    float m = dot4(kv0, p0) + dot4(kv1, p1);
    float n = dot4(qv0, p0) + dot4(qv1, p1);
    mp[j] = (j < t) ? m : 0.f;
    np[j] = (j <= t) ? n : 0.f;
  }
  row16_arr16(mp);
  row16_arr16(np);
#pragma unroll
  for (int j = 0; j < 16; j++) {
    if (kg == j) {
      Mb[t * 17 + j] = bls[t] * mp[j];
      preF[bF + t * 16 + j] = np[j];
    }
  }
  __syncthreads();  // Mb, khls, vls ready
  // ---- forward substitution, one column per thread (c<128: Khat; else v) ----
  const int c = tid;
  const float* src = (c < 128) ? &khls[c] : &vls[c - 128];
  float val[16];
#pragma unroll
  for (int tt = 0; tt < 16; tt++) {
    float a = 0.f;
#pragma unroll
    for (int j = 0; j < 16; j++)
      if (j < tt) a = fmaf(Mb[tt * 17 + j], val[j], a);
    val[tt] = fmaf(bls[tt], src[tt * 128], -a);
  }
  if (c < 128) {
#pragma unroll
    for (int tt = 0; tt < 16; tt++)
      preB[b16 + tt * 128 + c] = f2bf(val[tt]);  // TKh[t][c]
  } else {
    float4 v0 = {val[0], val[1], val[2], val[3]};
    float4 v1 = {val[4], val[5], val[6], val[7]};
    float4 v2 = {val[8], val[9], val[10], val[11]};
    float4 v3 = {val[12], val[13], val[14], val[15]};
    *(uint4*)(preB + b16 + 6144 + (c - 128) * 16) = pack8(v0, v1);      // Tvt[c][t]
    *(uint4*)(preB + b16 + 6144 + (c - 128) * 16 + 8) = pack8(v2, v3);
  }
}

// ---------------- KDA scan over windows: no serial substitution -------------
// 128 blocks x 128 threads: h = bx&7, colgroup cg = bx>>3 (8 v-cols each).
// lane: kg = lane&15 owns channels [kg*8, kg*8+8); colw = wave*4 + (lane>>4).
// Per window: aa=TKh.S, bb=Qhat.S (batched dots + 2 batched butterflies),
// vnw = Tv - aa, o = bb + N.vnw, S = Pbar*S + sum_j Kchk_j (x) vnw_j.
__global__ __launch_bounds__(128) void kda_scan(
    const uint16_t* __restrict__ preB, const float* __restrict__ preF,
    float* __restrict__ o) {
  __shared__ uint16_t Tls[2][8192];
  __shared__ float Nls[2][16 * 20];
  __shared__ float Pb2[2][128];
  const int h = blockIdx.x & 7, cg = blockIdx.x >> 3;
  const int tid = threadIdx.x;
  const int lane = tid & 63;
  const int kg = lane & 15;
  const int colw = (tid >> 6) * 4 + (lane >> 4);  // 0..7
  const int col = cg * 8 + colw;                  // 0..127

  uint4 rp16[8];
  float4 rn, rpb;
  auto load_g = [&](int w) {
    size_t b16 = (size_t)(w * 8 + h) * PREB_STRIDE;
    size_t bF = (size_t)(w * 8 + h) * PREF_STRIDE;
#pragma unroll
    for (int i = 0; i < 8; i++)
      rp16[i] = *(const uint4*)(preB + b16 + i * 1024 + tid * 8);
    if (tid < 64) rn = *(const float4*)(preF + bF + tid * 4);
    if (tid < 32) rpb = *(const float4*)(preF + bF + 256 + tid * 4);
  };
  auto commit = [&](int b) {
#pragma unroll
    for (int i = 0; i < 8; i++)
      *(uint4*)&Tls[b][i * 1024 + tid * 8] = rp16[i];
    if (tid < 64) *(float4*)&Nls[b][(tid >> 2) * 20 + (tid & 3) * 4] = rn;
    if (tid < 32) *(float4*)&Pb2[b][tid * 4] = rpb;
  };

  load_g(0);
  commit(0);
  __syncthreads();

  float4 sA = {0, 0, 0, 0}, sB = {0, 0, 0, 0};
  for (int w = 0; w < NWIN; w++) {
    const int cur = w & 1;
    const bool more = (w + 1 < NWIN);
    if (more) load_g(w + 1);
    // Tv for my column
    float tvv[16];
    {
      uint4 t0 = *(const uint4*)&Tls[cur][6144 + col * 16];
      uint4 t1 = *(const uint4*)&Tls[cur][6144 + col * 16 + 8];
      unp8(t0, &tvv[0]);
      unp8(t1, &tvv[8]);
    }
    // batched dots
    float aa[16], bb[16];
#pragma unroll
    for (int t = 0; t < 16; t++) {
      uint4 ut = *(const uint4*)&Tls[cur][t * 128 + kg * 8];
      uint4 uq = *(const uint4*)&Tls[cur][2048 + t * 128 + kg * 8];
      float tf[8], qf[8];
      unp8(ut, tf);
      unp8(uq, qf);
      float a = tf[0] * sA.x;
      a = fmaf(tf[1], sA.y, a); a = fmaf(tf[2], sA.z, a); a = fmaf(tf[3], sA.w, a);
      a = fmaf(tf[4], sB.x, a); a = fmaf(tf[5], sB.y, a);
      a = fmaf(tf[6], sB.z, a); a = fmaf(tf[7], sB.w, a);
      float b = qf[0] * sA.x;
      b = fmaf(qf[1], sA.y, b); b = fmaf(qf[2], sA.z, b); b = fmaf(qf[3], sA.w, b);
      b = fmaf(qf[4], sB.x, b); b = fmaf(qf[5], sB.y, b);
      b = fmaf(qf[6], sB.z, b); b = fmaf(qf[7], sB.w, b);
      aa[t] = a;
      bb[t] = b;
    }
    row16_arr16(aa);
    row16_arr16(bb);
    float vnw[16];
#pragma unroll
    for (int t = 0; t < 16; t++) vnw[t] = tvv[t] - aa[t];
    // outputs: o_t = bb_t + sum_{j<=t} N[t][j] vnw[j]
#pragma unroll
    for (int t = 0; t < 16; t++) {
      float nr[16];
      *(float4*)&nr[0] = *(const float4*)&Nls[cur][t * 20 + 0];
      *(float4*)&nr[4] = *(const float4*)&Nls[cur][t * 20 + 4];
      *(float4*)&nr[8] = *(const float4*)&Nls[cur][t * 20 + 8];
      *(float4*)&nr[12] = *(const float4*)&Nls[cur][t * 20 + 12];
      float ot = bb[t];
#pragma unroll
      for (int jj = 0; jj <= t; jj++) ot = fmaf(nr[jj], vnw[jj], ot);
      if (kg == 0)
        o[(size_t)(w * 16 + t) * KD_ + h * DK_ + col] = ot;
    }
    // state update
    {
      float4 p0 = *(const float4*)&Pb2[cur][kg * 8];
      float4 p1 = *(const float4*)&Pb2[cur][kg * 8 + 4];
      sA = f4mul(sA, p0);
      sB = f4mul(sB, p1);
#pragma unroll
      for (int jj = 0; jj < 16; jj++) {
        uint4 uc = *(const uint4*)&Tls[cur][4096 + jj * 128 + kg * 8];
        float cf[8];
        unp8(uc, cf);
        float4 c0 = {cf[0], cf[1], cf[2], cf[3]};
        float4 c1 = {cf[4], cf[5], cf[6], cf[7]};
        sA = f4fma(c0, vnw[jj], sA);
        sB = f4fma(c1, vnw[jj], sB);
      }
    }
    if (more) commit(cur ^ 1);
    __syncthreads();
  }
}

// ---- FusedRMSNormGated: gate = sigmoid(g2raw + bg2) fused; bf16 out ----
__global__ __launch_bounds__(64) void gated_rmsnorm(
    const float* __restrict__ o, const float* __restrict__ g2raw,
    const float* __restrict__ bg2, const float* __restrict__ wn,
    uint16_t* __restrict__ ob) {
  size_t base = (size_t)blockIdx.x * DV_;
  int t = threadIdx.x;
  float a = o[base + t], b = o[base + t + 64];
  float ss = a * a + b * b;
#pragma unroll
  for (int off = 32; off > 0; off >>= 1) ss += __shfl_xor(ss, off);
  float r = rsqrtf(ss * (1.f / 128.f) + 1e-5f);
  int c0 = (int)((base + t) & 1023), c1 = (int)((base + t + 64) & 1023);
  float ga = 1.f / (1.f + expf(-(g2raw[base + t] + bg2[c0])));
  float gb = 1.f / (1.f + expf(-(g2raw[base + t + 64] + bg2[c1])));
  ob[base + t] = f2bf(a * r * wn[t] * ga);
  ob[base + t + 64] = f2bf(b * r * wn[t + 64] * gb);
}

extern "C" void kernel_launch(void* const* d_in, const int* in_sizes, int n_in,
                              void* d_out, int out_size, void* d_ws, size_t ws_size,
                              hipStream_t stream) {
  const float* x = (const float*)d_in[0];
  const float* ve = (const float*)d_in[1];
  const float* lam = (const float*)d_in[2];
  const float* Wq = (const float*)d_in[3];
  const float* Wk = (const float*)d_in[4];
  const float* Wv = (const float*)d_in[5];
  const float* Wo = (const float*)d_in[6];
  const float* wq_conv = (const float*)d_in[7];
  const float* wk_conv = (const float*)d_in[8];
  const float* wv_conv = (const float*)d_in[9];
  const float* Wf1 = (const float*)d_in[10];
  const float* Wf2 = (const float*)d_in[11];
  const float* Wb = (const float*)d_in[12];
  const float* A_log = (const float*)d_in[13];
  const float* dt_bias = (const float*)d_in[14];
  const float* Wg1 = (const float*)d_in[15];
  const float* Wg2 = (const float*)d_in[16];
  const float* bg2 = (const float*)d_in[17];
  const float* w_norm = (const float*)d_in[18];
  float* out = (float*)d_out;

  float* ws = (float*)d_ws;
  const size_t SZ = (size_t)S_LEN * KD_;  // 2M floats
  float* q_pre = ws;
  float* k_pre = ws + SZ;
  float* v_pre = ws + 2 * SZ;
  float* ve_pre = ws + 3 * SZ;
  float* q_c = ws + 4 * SZ;
  float* k_c = ws + 5 * SZ;
  float* v_mix = ws + 6 * SZ;
  float* f1 = ve_pre;                              // [S,128] after conv
  float* bpre = ve_pre + 2 * (size_t)S_LEN * DV_;  // [S,8] raw
  float* graw = q_pre;                             // -> raw g in place
  float* g2raw = k_pre;                            // raw gate pre-activation
  float* o_buf = v_pre;
  uint16_t* bws = (uint16_t*)(ws + 7 * SZ);
  uint16_t* xb = bws;
  uint16_t* veb = xb + SZ;
  uint16_t* Wqb = veb + SZ;
  uint16_t* Wkb = Wqb + (size_t)KD_ * DMODEL;
  uint16_t* Wvb = Wkb + (size_t)KD_ * DMODEL;
  uint16_t* Wob = Wvb + (size_t)KD_ * DMODEL;
  uint16_t* Wg1b = Wob + (size_t)DMODEL * KD_;
  uint16_t* Wg2b = Wg1b + (size_t)DV_ * DMODEL;
  uint16_t* g1b = Wg2b + (size_t)KD_ * DV_;        // [S,128] bf16
  uint16_t* ob = g1b + (size_t)S_LEN * DV_;        // [S,1024] bf16
  // pre buffers at 20M floats (proven-safe region from round 5)
  uint16_t* preB = (uint16_t*)(ws + (size_t)20 * 1024 * 1024);  // 1024*8192 u16 = 16MB
  float* preF = ws + (size_t)20 * 1024 * 1024 + (size_t)4 * 1024 * 1024 + 64;
  // (preB occupies 4M float-slots; preF 1024*384 floats = 1.5MB; +64 pad)

  dim3 blk(256);
  int ew_blocks = (S_LEN * KD_ + 255) / 256;

  CastArgs ca;
  ca.s[0] = x;   ca.d[0] = xb;   ca.n[0] = S_LEN * DMODEL;
  ca.s[1] = ve;  ca.d[1] = veb;  ca.n[1] = S_LEN * DMODEL;
  ca.s[2] = Wq;  ca.d[2] = Wqb;  ca.n[2] = KD_ * DMODEL;
  ca.s[3] = Wk;  ca.d[3] = Wkb;  ca.n[3] = KD_ * DMODEL;
  ca.s[4] = Wv;  ca.d[4] = Wvb;  ca.n[4] = KD_ * DMODEL;
  ca.s[5] = Wo;  ca.d[5] = Wob;  ca.n[5] = DMODEL * KD_;
  ca.s[6] = Wg1; ca.d[6] = Wg1b; ca.n[6] = DV_ * DMODEL;
  ca.s[7] = Wg2; ca.d[7] = Wg2b; ca.n[7] = KD_ * DV_;
  cast_multi<<<dim3(1024, 8), blk, 0, stream>>>(ca);

  GJobs jq;
  jq.A[0] = xb;  jq.B[0] = Wqb;  jq.C[0] = q_pre;  jq.N[0] = KD_; jq.outbf[0] = 0;
  jq.A[1] = xb;  jq.B[1] = Wkb;  jq.C[1] = k_pre;  jq.N[1] = KD_; jq.outbf[1] = 0;
  jq.A[2] = xb;  jq.B[2] = Wvb;  jq.C[2] = v_pre;  jq.N[2] = KD_; jq.outbf[2] = 0;
  jq.A[3] = veb; jq.B[3] = Wvb;  jq.C[3] = ve_pre; jq.N[3] = KD_; jq.outbf[3] = 0;
  jq.A[4] = xb;  jq.B[4] = Wg1b; jq.C[4] = g1b;    jq.N[4] = DV_; jq.outbf[4] = 1;
  gemm_mfma<<<dim3(8, 16, 5), blk, 0, stream>>>(jq, DMODEL);

  conv_silu_mix<<<ew_blocks, blk, 0, stream>>>(q_pre, k_pre, v_pre, ve_pre,
                                               wq_conv, wk_conv, wv_conv, lam,
                                               q_c, k_c, v_mix);

  gemm_abt<<<dim3(2, 32), blk, 0, stream>>>(x, Wf1, f1, S_LEN, DV_, DMODEL);
  gemm_abt<<<dim3(1, 32), blk, 0, stream>>>(x, Wb, bpre, S_LEN, NH, DMODEL);
  gemm_abt<<<dim3(16, 32), blk, 0, stream>>>(f1, Wf2, graw, S_LEN, KD_, DV_);
  g_only<<<ew_blocks, blk, 0, stream>>>(graw, dt_bias, A_log);

  kda_pre<<<dim3(NWIN * 8), blk, 0, stream>>>(q_c, k_c, graw, v_mix, bpre,
                                              preB, preF);
  kda_scan<<<dim3(128), dim3(128), 0, stream>>>(preB, preF, o_buf);

  GJobs jg2;
  jg2.A[0] = g1b; jg2.B[0] = Wg2b; jg2.C[0] = g2raw; jg2.N[0] = KD_; jg2.outbf[0] = 0;
  gemm_mfma<<<dim3(8, 16, 1), blk, 0, stream>>>(jg2, DV_);

  gated_rmsnorm<<<dim3(S_LEN * NH), dim3(64), 0, stream>>>(o_buf, g2raw, bg2,
                                                           w_norm, ob);

  GJobs jo;
  jo.A[0] = ob; jo.B[0] = Wob; jo.C[0] = out; jo.N[0] = DMODEL; jo.outbf[0] = 0;
  gemm_mfma<<<dim3(8, 16, 1), blk, 0, stream>>>(jo, KD_);
}

// Round 7
// 646.903 us; speedup vs baseline: 1.6940x; 1.5197x over previous
//
#include <hip/hip_runtime.h>
#include <math.h>
#include <stdint.h>

#define S_LEN 2048
#define DMODEL 1024
#define NH 8
#define DK_ 128
#define DV_ 128
#define KD_ 1024
#define KCONV 4
#define CW 32     // chunk (window) length
#define NW2 64    // number of windows
// per-(w,h) bf16 block: TKh[32][128] | Qhat[32][128] | KchkT[128][32] | Tv[32][128] | N[32][32]
#define PREB_STRIDE 17408
#define TKH_OFF 0
#define QHT_OFF 4096
#define KCT_OFF 8192
#define TV_OFF 12288
#define NN_OFF 16384

typedef short bf16x8 __attribute__((ext_vector_type(8)));
typedef float f32x4 __attribute__((ext_vector_type(4)));

__device__ __forceinline__ uint16_t f2bf(float f) {  // RNE
  uint32_t u = __float_as_uint(f);
  u += 0x7FFF + ((u >> 16) & 1);
  return (uint16_t)(u >> 16);
}
__device__ __forceinline__ float bf2f(uint16_t u) {
  return __uint_as_float((uint32_t)u << 16);
}
__device__ __forceinline__ void glds16(const uint16_t* g, uint16_t* l) {
  __builtin_amdgcn_global_load_lds(
      (const __attribute__((address_space(1))) void*)g,
      (__attribute__((address_space(3))) void*)l, 16, 0, 0);
}
__device__ __forceinline__ float dot4(float4 a, float4 b) {
  return fmaf(a.w, b.w, fmaf(a.z, b.z, fmaf(a.y, b.y, a.x * b.x)));
}
__device__ __forceinline__ float4 f4add(float4 a, float4 b) {
  float4 r; r.x = a.x + b.x; r.y = a.y + b.y; r.z = a.z + b.z; r.w = a.w + b.w; return r;
}
__device__ __forceinline__ float4 f4sub(float4 a, float4 b) {
  float4 r; r.x = a.x - b.x; r.y = a.y - b.y; r.z = a.z - b.z; r.w = a.w - b.w; return r;
}
__device__ __forceinline__ float4 f4mul(float4 a, float4 b) {
  float4 r; r.x = a.x * b.x; r.y = a.y * b.y; r.z = a.z * b.z; r.w = a.w * b.w; return r;
}
__device__ __forceinline__ float4 f4s(float4 a, float s) {
  float4 r; r.x = a.x * s; r.y = a.y * s; r.z = a.z * s; r.w = a.w * s; return r;
}
__device__ __forceinline__ float4 f4expc(float4 a) {  // exp(min(a,0)) — overflow-safe
  float4 r;
  r.x = expf(fminf(a.x, 0.f)); r.y = expf(fminf(a.y, 0.f));
  r.z = expf(fminf(a.z, 0.f)); r.w = expf(fminf(a.w, 0.f));
  return r;
}
__device__ __forceinline__ float4 f4exp(float4 a) {
  float4 r; r.x = expf(a.x); r.y = expf(a.y); r.z = expf(a.z); r.w = expf(a.w); return r;
}
__device__ __forceinline__ uint4 pack8(float4 a, float4 b) {
  uint4 r;
  r.x = (uint32_t)f2bf(a.x) | ((uint32_t)f2bf(a.y) << 16);
  r.y = (uint32_t)f2bf(a.z) | ((uint32_t)f2bf(a.w) << 16);
  r.z = (uint32_t)f2bf(b.x) | ((uint32_t)f2bf(b.y) << 16);
  r.w = (uint32_t)f2bf(b.z) | ((uint32_t)f2bf(b.w) << 16);
  return r;
}
__device__ __forceinline__ uint2 pack4(f32x4 a) {
  uint2 r;
  r.x = (uint32_t)f2bf(a[0]) | ((uint32_t)f2bf(a[1]) << 16);
  r.y = (uint32_t)f2bf(a[2]) | ((uint32_t)f2bf(a[3]) << 16);
  return r;
}
union U4B8 { uint4 u; bf16x8 b; };
__device__ __forceinline__ bf16x8 u2b(uint4 u) { U4B8 x; x.u = u; return x.b; }

#define DPPADD(x, ctrl) \
  x += __int_as_float(__builtin_amdgcn_update_dpp(0, __float_as_int(x), ctrl, 0xF, 0xF, true))

// reduction over 8 consecutive lanes (xor1, xor2, half-mirror)
__device__ __forceinline__ void row8_sum2(float& a, float& b) {
  DPPADD(a, 0xB1); DPPADD(b, 0xB1);
  DPPADD(a, 0x4E); DPPADD(b, 0x4E);
  DPPADD(a, 0x141); DPPADD(b, 0x141);
}
__device__ __forceinline__ void row8_arr32(float* x) {
#pragma unroll
  for (int i = 0; i < 32; i++) DPPADD(x[i], 0xB1);
#pragma unroll
  for (int i = 0; i < 32; i++) DPPADD(x[i], 0x4E);
#pragma unroll
  for (int i = 0; i < 32; i++) DPPADD(x[i], 0x141);
}

// ---------------- fused fp32 -> bf16 cast for up to 8 tensors ----------------
struct CastArgs {
  const float* s[8];
  uint16_t* d[8];
  int n[8];
};
__global__ __launch_bounds__(256) void cast_multi(CastArgs a) {
  int i = blockIdx.y;
  int base = (blockIdx.x * 256 + threadIdx.x) * 8;
  if (base >= a.n[i]) return;
  const float4* sp = (const float4*)(a.s[i] + base);
  float4 x0 = sp[0], x1 = sp[1];
  uint4 v = pack8(x0, x1);
  *(uint4*)(a.d[i] + base) = v;
}

// ---------------- bf16 MFMA GEMM: C[M,N] = A[M,K] @ B[N,K]^T ----------------
struct GJobs {
  const uint16_t* A[5];
  const uint16_t* B[5];
  void* C[5];
  int N[5];
  int outbf[5];
};
__global__ __launch_bounds__(256) void gemm_mfma(GJobs j, int K) {
  const int z = blockIdx.z;
  const int N = j.N[z];
  const int n0 = blockIdx.x * 128;
  if (n0 >= N) return;
  __shared__ uint16_t Asb[128 * 32];
  __shared__ uint16_t Bsb[128 * 32];
  const uint16_t* __restrict__ A = j.A[z];
  const uint16_t* __restrict__ B = j.B[z];
  const int tid = threadIdx.x;
  const int w = tid >> 6, lane = tid & 63;
  const int m0 = blockIdx.y * 128;
  const int mw = (w & 1) * 64, nw = (w >> 1) * 64;
  const int c0 = tid, c1 = 256 + tid;
  const int r0 = c0 >> 2, cl0 = (c0 & 3) ^ ((r0 >> 2) & 3);
  const int r1 = c1 >> 2, cl1 = (c1 & 3) ^ ((r1 >> 2) & 3);
  const uint16_t* gA0 = A + (size_t)(m0 + r0) * K + cl0 * 8;
  const uint16_t* gA1 = A + (size_t)(m0 + r1) * K + cl1 * 8;
  const uint16_t* gB0 = B + (size_t)(n0 + r0) * K + cl0 * 8;
  const uint16_t* gB1 = B + (size_t)(n0 + r1) * K + cl1 * 8;
  uint16_t* lA0 = Asb + w * 512;
  uint16_t* lA1 = Asb + 2048 + w * 512;
  uint16_t* lB0 = Bsb + w * 512;
  uint16_t* lB1 = Bsb + 2048 + w * 512;

  const int l15 = lane & 15, q = lane >> 4;
  const int ccq = q ^ ((l15 >> 2) & 3);

  f32x4 acc[4][4] = {};
  for (int k0 = 0; k0 < K; k0 += 32) {
    glds16(gA0 + k0, lA0);
    glds16(gA1 + k0, lA1);
    glds16(gB0 + k0, lB0);
    glds16(gB1 + k0, lB1);
    __syncthreads();
    bf16x8 af[4], bfr[4];
#pragma unroll
    for (int i = 0; i < 4; i++)
      af[i] = *(const bf16x8*)&Asb[(mw + i * 16 + l15) * 32 + ccq * 8];
#pragma unroll
    for (int jx = 0; jx < 4; jx++)
      bfr[jx] = *(const bf16x8*)&Bsb[(nw + jx * 16 + l15) * 32 + ccq * 8];
#pragma unroll
    for (int i = 0; i < 4; i++)
#pragma unroll
      for (int jx = 0; jx < 4; jx++)
        acc[i][jx] = __builtin_amdgcn_mfma_f32_16x16x32_bf16(af[i], bfr[jx],
                                                             acc[i][jx], 0, 0, 0);
    __syncthreads();
  }
  const int obf = j.outbf[z];
#pragma unroll
  for (int i = 0; i < 4; i++) {
#pragma unroll
    for (int jx = 0; jx < 4; jx++) {
      int n = n0 + nw + jx * 16 + l15;
#pragma unroll
      for (int r = 0; r < 4; r++) {
        int m = m0 + mw + i * 16 + q * 4 + r;
        if (obf)
          ((uint16_t*)j.C[z])[(size_t)m * N + n] = f2bf(acc[i][jx][r]);
        else
          ((float*)j.C[z])[(size_t)m * N + n] = acc[i][jx][r];
      }
    }
  }
}

// ---------------- fp32 GEMM (numerically-sensitive g-path + Wb) -----
__global__ __launch_bounds__(256) void gemm_abt(
    const float* __restrict__ A, const float* __restrict__ B,
    float* __restrict__ C, int M, int N, int Kd) {
  __shared__ float As[16][68];
  __shared__ float Bs[16][68];
  const int tid = threadIdx.x;
  const int m0 = blockIdx.y * 64, n0 = blockIdx.x * 64;
  const int tx = tid & 15, ty = tid >> 4;
  const int lk = tid & 15, lr = tid >> 4;
  float acc[4][4] = {};
  for (int k0 = 0; k0 < Kd; k0 += 16) {
#pragma unroll
    for (int i = 0; i < 4; i++) {
      int m = m0 + lr + 16 * i;
      As[lk][lr + 16 * i] = (m < M) ? A[(size_t)m * Kd + k0 + lk] : 0.f;
      int n = n0 + lr + 16 * i;
      Bs[lk][lr + 16 * i] = (n < N) ? B[(size_t)n * Kd + k0 + lk] : 0.f;
    }
    __syncthreads();
#pragma unroll
    for (int kk = 0; kk < 16; kk++) {
      float4 a4 = *(const float4*)&As[kk][ty * 4];
      float4 b4 = *(const float4*)&Bs[kk][tx * 4];
      float av[4] = {a4.x, a4.y, a4.z, a4.w};
      float bv[4] = {b4.x, b4.y, b4.z, b4.w};
#pragma unroll
      for (int i = 0; i < 4; i++)
#pragma unroll
        for (int jx = 0; jx < 4; jx++) acc[i][jx] = fmaf(av[i], bv[jx], acc[i][jx]);
    }
    __syncthreads();
  }
#pragma unroll
  for (int i = 0; i < 4; i++) {
    int m = m0 + ty * 4 + i;
    if (m >= M) continue;
#pragma unroll
    for (int jx = 0; jx < 4; jx++) {
      int n = n0 + tx * 4 + jx;
      if (n < N) C[(size_t)m * N + n] = acc[i][jx];
    }
  }
}

// -------- depthwise causal conv(K=4) + silu for q,k,v and ve; mix v ----------
__global__ __launch_bounds__(256) void conv_silu_mix(
    const float* __restrict__ qp, const float* __restrict__ kp,
    const float* __restrict__ vp, const float* __restrict__ vep,
    const float* __restrict__ wq, const float* __restrict__ wk,
    const float* __restrict__ wv, const float* __restrict__ lam,
    float* __restrict__ qc, float* __restrict__ kc, float* __restrict__ vmx) {
  int idx = blockIdx.x * 256 + threadIdx.x;
  if (idx >= S_LEN * KD_) return;
  int s = idx >> 10, d = idx & 1023;
  float aq = 0.f, ak = 0.f, av = 0.f, ae = 0.f;
#pragma unroll
  for (int i = 0; i < KCONV; i++) {
    int ss = s - (KCONV - 1) + i;
    if (ss < 0) continue;
    size_t off = (size_t)ss * KD_ + d;
    aq = fmaf(qp[off], wq[d * KCONV + i], aq);
    ak = fmaf(kp[off], wk[d * KCONV + i], ak);
    av = fmaf(vp[off], wv[d * KCONV + i], av);
    ae = fmaf(vep[off], wv[d * KCONV + i], ae);
  }
  qc[idx] = aq / (1.f + expf(-aq));
  kc[idx] = ak / (1.f + expf(-ak));
  float sv = av / (1.f + expf(-av));
  float se = ae / (1.f + expf(-ae));
  vmx[idx] = lam[0] * sv + lam[1] * se;
}

// ------ g = -exp(A_log)*softplus(graw+dt_bias), in place (raw g) ------
__global__ __launch_bounds__(256) void g_only(
    float* __restrict__ graw, const float* __restrict__ dt_bias,
    const float* __restrict__ A_log) {
  int idx = blockIdx.x * 256 + threadIdx.x;
  if (idx >= S_LEN * KD_) return;
  int c = idx & 1023;
  float xv = graw[idx] + dt_bias[c];
  float sp = (xv > 20.f) ? xv : log1pf(expf(xv));
  graw[idx] = -expf(A_log[c >> 7]) * sp;
}

// ---------------- KDA window precompute, C=32 (fully parallel) ----------------
// 512 blocks (w,h) x 256 threads (t = tid>>3 in [0,32), kq = tid&7 owns 16 ch).
// Emits MFMA-ready bf16 operands: TKh [t][k], Qhat [t][k], KchkT [k][t],
// Tv [t][c], N [t][j] (j<=t, else 0); Pbar fp32 [k].
__global__ __launch_bounds__(256) void kda_pre(
    const float* __restrict__ qc, const float* __restrict__ kc,
    const float* __restrict__ g, const float* __restrict__ vm,
    const float* __restrict__ bpre, uint16_t* __restrict__ preB,
    float* __restrict__ preF) {
  __shared__ float kls[32 * 128];   // normalized k [t][c]
  __shared__ float Gls[32 * 128];   // raw g, then (after barrier) cumsum G_t
  __shared__ float khls[32 * 128];  // Khat [t][c]
  __shared__ float Mcm[32 * 36];    // column-major beta-folded M: Mcm[j][t2]
  __shared__ float bls[32];
  const int w = blockIdx.x >> 3, h = blockIdx.x & 7;
  const int tid = threadIdx.x;
  const int t = tid >> 3, kq = tid & 7;
  const size_t gb = (size_t)blockIdx.x * PREB_STRIDE;
  const size_t gf = (size_t)blockIdx.x * 128;

  size_t roff = (size_t)(w * CW + t) * KD_ + h * DK_ + kq * 16;
  float4 kv[4], qv[4], gv[4];
#pragma unroll
  for (int i = 0; i < 4; i++) {
    kv[i] = *(const float4*)(kc + roff + i * 4);
    qv[i] = *(const float4*)(qc + roff + i * 4);
    gv[i] = *(const float4*)(g + roff + i * 4);
  }
  if (tid < 32) {
    float b = bpre[(size_t)(w * CW + tid) * NH + h];
    bls[tid] = 1.f / (1.f + expf(-b));
  }
  // v column preload for fwd-sub threads (c = tid >= 128)
  float src[32];
  if (tid >= 128) {
    int c2 = tid - 128;
#pragma unroll
    for (int t2 = 0; t2 < 32; t2++)
      src[t2] = vm[(size_t)(w * CW + t2) * KD_ + h * DV_ + c2];
  }
  // fused l2norm (16 ch partial + 8-lane reduction)
  float sk = 0.f, sq = 0.f;
#pragma unroll
  for (int i = 0; i < 4; i++) {
    sk += dot4(kv[i], kv[i]);
    sq += dot4(qv[i], qv[i]);
  }
  row8_sum2(sk, sq);
  float rkn = rsqrtf(sk + 1e-6f);
  float rqn = rsqrtf(sq + 1e-6f) * 0.08838834764831845f;  // * DK^-0.5
#pragma unroll
  for (int i = 0; i < 4; i++) {
    kv[i] = f4s(kv[i], rkn);
    qv[i] = f4s(qv[i], rqn);
    *(float4*)&kls[t * 128 + kq * 16 + i * 4] = kv[i];
    *(float4*)&Gls[t * 128 + kq * 16 + i * 4] = gv[i];
  }
  __syncthreads();
  // inclusive cumsum G_t and full sum Gf over own 16 channels
  float4 Ga[4] = {}, Gf[4] = {};
#pragma unroll
  for (int j = 0; j < 32; j++) {
#pragma unroll
    for (int i = 0; i < 4; i++) {
      float4 gj = *(const float4*)&Gls[j * 128 + kq * 16 + i * 4];
      Gf[i] = f4add(Gf[i], gj);
      if (j <= t) Ga[i] = f4add(Ga[i], gj);
    }
  }
  __syncthreads();  // everyone done with raw g
  float4 Pa[4], ea[4];
#pragma unroll
  for (int i = 0; i < 4; i++) {
    *(float4*)&Gls[t * 128 + kq * 16 + i * 4] = Ga[i];  // overwrite with cumsum
    Pa[i] = f4exp(Ga[i]);
    ea[i] = f4exp(f4sub(Gf[i], Ga[i]));
    float4 kh = f4mul(kv[i], Pa[i]);
    *(float4*)&khls[t * 128 + kq * 16 + i * 4] = kh;
  }
  // Qhat global (bf16, [t][k])
  {
    float4 q0 = f4mul(qv[0], Pa[0]), q1 = f4mul(qv[1], Pa[1]);
    float4 q2 = f4mul(qv[2], Pa[2]), q3 = f4mul(qv[3], Pa[3]);
    *(uint4*)(preB + gb + QHT_OFF + t * 128 + kq * 16) = pack8(q0, q1);
    *(uint4*)(preB + gb + QHT_OFF + t * 128 + kq * 16 + 8) = pack8(q2, q3);
  }
  // KchkT global (bf16, [k][t]) — transposed scalar stores
  {
    float kk[16];
#pragma unroll
    for (int i = 0; i < 4; i++) {
      float4 kc4 = f4mul(kv[i], ea[i]);
      kk[i * 4 + 0] = kc4.x; kk[i * 4 + 1] = kc4.y;
      kk[i * 4 + 2] = kc4.z; kk[i * 4 + 3] = kc4.w;
    }
#pragma unroll
    for (int i = 0; i < 16; i++)
      preB[gb + KCT_OFF + (kq * 16 + i) * 32 + t] = f2bf(kk[i]);
  }
  if (t == 31) {
#pragma unroll
    for (int i = 0; i < 4; i++)
      *(float4*)(preF + gf + kq * 16 + i * 4) = Pa[i];
  }
  __syncthreads();  // Gls = cumsum, khls ready
  // M (strict lower, -> LDS col-major beta-folded) and N (j<=t, -> global bf16)
  float mp[32], np[32];
#pragma unroll
  for (int j = 0; j < 32; j++) {
    float m = 0.f, n = 0.f;
#pragma unroll
    for (int i = 0; i < 4; i++) {
      float4 kj = *(const float4*)&kls[j * 128 + kq * 16 + i * 4];
      float4 Gj = *(const float4*)&Gls[j * 128 + kq * 16 + i * 4];
      float4 e = f4expc(f4sub(Ga[i], Gj));
      float4 p = f4mul(kj, e);
      m += dot4(kv[i], p);
      n += dot4(qv[i], p);
    }
    mp[j] = (j < t) ? m : 0.f;
    np[j] = (j <= t) ? n : 0.f;
  }
  row8_arr32(mp);
  row8_arr32(np);
#pragma unroll
  for (int jj = 0; jj < 4; jj++) {
    int j = jj * 8 + kq;
    Mcm[j * 36 + t] = bls[t] * mp[j];
    preB[gb + NN_OFF + t * 32 + j] = f2bf(np[j]);
  }
  // fwd-sub source for Khat columns
  float bl[32];
#pragma unroll
  for (int i = 0; i < 8; i++) {
    float4 b4 = *(const float4*)&bls[i * 4];
    bl[i * 4 + 0] = b4.x; bl[i * 4 + 1] = b4.y;
    bl[i * 4 + 2] = b4.z; bl[i * 4 + 3] = b4.w;
  }
  if (tid < 128) {
#pragma unroll
    for (int t2 = 0; t2 < 32; t2++) src[t2] = khls[t2 * 128 + tid];
  }
  __syncthreads();  // Mcm ready
  // forward substitution: one column per thread (c<128: TKh, c>=128: Tv)
  const int c = tid;
  float acc[32];
#pragma unroll
  for (int i = 0; i < 32; i++) acc[i] = 0.f;
#pragma unroll
  for (int t2 = 0; t2 < 32; t2++) {
    float val = fmaf(bl[t2], src[t2], -acc[t2]);
    if (c < 128)
      preB[gb + TKH_OFF + t2 * 128 + c] = f2bf(val);
    else
      preB[gb + TV_OFF + t2 * 128 + (c - 128)] = f2bf(val);
#pragma unroll
    for (int t3 = t2 + 1; t3 < 32; t3++)
      acc[t3] = fmaf(Mcm[t2 * 36 + t3], val, acc[t3]);
  }
}

// ---------------- KDA scan over windows: MFMA, C=32 ----------------
// 64 blocks (h = bx&7 -> same-head blocks share XCD; cg = bx>>3 picks 16 cols).
// 128 threads: wave0 = compute (26 MFMA/window, state fp32 in acc regs),
// wave1 = staging (global->LDS double-buffer of TKh/Qhat).
__global__ __launch_bounds__(128) void kda_scan(
    const uint16_t* __restrict__ preB, const float* __restrict__ preF,
    float* __restrict__ o) {
  __shared__ uint16_t tkh[2][32 * 136];
  __shared__ uint16_t qht[2][32 * 136];
  __shared__ uint16_t sbf[16 * 136];  // S as B-operand [c][k]
  __shared__ uint16_t vbf[16 * 40];   // vnw as B-operand [c][j]
  const int h = blockIdx.x & 7, cg = blockIdx.x >> 3;
  const int tid = threadIdx.x;
  const int wv = tid >> 6, lane = tid & 63;
  const int q = lane >> 4, l15 = lane & 15;

  auto stage = [&](int w, int buf) {
    size_t gbs = (size_t)(w * 8 + h) * PREB_STRIDE;
    const uint4* gt = (const uint4*)(preB + gbs + TKH_OFF);
    const uint4* gq = (const uint4*)(preB + gbs + QHT_OFF);
    int row = lane >> 1, half = lane & 1;
    uint4 a[8], b[8];
#pragma unroll
    for (int i = 0; i < 8; i++) {
      a[i] = gt[lane * 8 + i];
      b[i] = gq[lane * 8 + i];
    }
#pragma unroll
    for (int i = 0; i < 8; i++) {
      *(uint4*)&tkh[buf][row * 136 + half * 64 + i * 8] = a[i];
      *(uint4*)&qht[buf][row * 136 + half * 64 + i * 8] = b[i];
    }
  };

  f32x4 s[8] = {};  // state slice: 8 k-tiles x [16k x 16c], C-layout

  if (wv == 1) stage(0, 0);
  __syncthreads();

  for (int w = 0; w < NW2; w++) {
    if (wv == 1) {
      if (w + 1 < NW2) stage(w + 1, (w + 1) & 1);
    } else {
      const int buf = w & 1;
      const size_t gbs = (size_t)(w * 8 + h) * PREB_STRIDE;
      // --- prefetch small operands from global (L2-hot) ---
      uint4 kct[8], nrg[2];
      float4 pb[8];
      float tvv[2][4];
#pragma unroll
      for (int ki = 0; ki < 8; ki++)
        kct[ki] = *(const uint4*)(preB + gbs + KCT_OFF + (16 * ki + l15) * 32 + q * 8);
#pragma unroll
      for (int tt = 0; tt < 2; tt++)
        nrg[tt] = *(const uint4*)(preB + gbs + NN_OFF + (tt * 16 + l15) * 32 + q * 8);
#pragma unroll
      for (int ki = 0; ki < 8; ki++)
        pb[ki] = *(const float4*)(preF + (size_t)(w * 8 + h) * 128 + 16 * ki + q * 4);
#pragma unroll
      for (int tt = 0; tt < 2; tt++)
#pragma unroll
        for (int r = 0; r < 4; r++)
          tvv[tt][r] = bf2f(preB[gbs + TV_OFF + (tt * 16 + q * 4 + r) * 128 + cg * 16 + l15]);
      // --- S -> bf16 B-operand scratch ([c][k], stride 136) ---
#pragma unroll
      for (int ki = 0; ki < 8; ki++)
        *(uint2*)&sbf[l15 * 136 + 16 * ki + q * 4] = pack4(s[ki]);
      // --- aa/bb: 16 MFMA over 4 k-chunks x 2 t-tiles ---
      f32x4 aat[2] = {}, bbt[2] = {};
#pragma unroll
      for (int kc = 0; kc < 4; kc++) {
        bf16x8 bS = *(const bf16x8*)&sbf[l15 * 136 + kc * 32 + q * 8];
#pragma unroll
        for (int tt = 0; tt < 2; tt++) {
          bf16x8 aT = *(const bf16x8*)&tkh[buf][(tt * 16 + l15) * 136 + kc * 32 + q * 8];
          bf16x8 aQ = *(const bf16x8*)&qht[buf][(tt * 16 + l15) * 136 + kc * 32 + q * 8];
          aat[tt] = __builtin_amdgcn_mfma_f32_16x16x32_bf16(aT, bS, aat[tt], 0, 0, 0);
          bbt[tt] = __builtin_amdgcn_mfma_f32_16x16x32_bf16(aQ, bS, bbt[tt], 0, 0, 0);
        }
      }
      // --- vnw = Tv - aa ; to bf16 B-operand scratch ([c][j], stride 40) ---
#pragma unroll
      for (int tt = 0; tt < 2; tt++) {
        f32x4 vn;
#pragma unroll
        for (int r = 0; r < 4; r++) vn[r] = tvv[tt][r] - aat[tt][r];
        *(uint2*)&vbf[l15 * 40 + tt * 16 + q * 4] = pack4(vn);
      }
      bf16x8 bV = *(const bf16x8*)&vbf[l15 * 40 + q * 8];
      // --- o = bb + N.vnw ---
#pragma unroll
      for (int tt = 0; tt < 2; tt++) {
        f32x4 ot = __builtin_amdgcn_mfma_f32_16x16x32_bf16(u2b(nrg[tt]), bV,
                                                           bbt[tt], 0, 0, 0);
#pragma unroll
        for (int r = 0; r < 4; r++)
          o[(size_t)(w * CW + tt * 16 + q * 4 + r) * KD_ + h * DK_ + cg * 16 + l15] = ot[r];
      }
      // --- S = Pbar*S + KchkT . vnw ---
#pragma unroll
      for (int ki = 0; ki < 8; ki++) {
#pragma unroll
        for (int r = 0; r < 4; r++) s[ki][r] *= pb[ki][r];
        s[ki] = __builtin_amdgcn_mfma_f32_16x16x32_bf16(u2b(kct[ki]), bV, s[ki], 0, 0, 0);
      }
    }
    __syncthreads();
  }
}

// ---- FusedRMSNormGated: gate = sigmoid(g2raw + bg2) fused; bf16 out ----
__global__ __launch_bounds__(64) void gated_rmsnorm(
    const float* __restrict__ o, const float* __restrict__ g2raw,
    const float* __restrict__ bg2, const float* __restrict__ wn,
    uint16_t* __restrict__ ob) {
  size_t base = (size_t)blockIdx.x * DV_;
  int t = threadIdx.x;
  float a = o[base + t], b = o[base + t + 64];
  float ss = a * a + b * b;
#pragma unroll
  for (int off = 32; off > 0; off >>= 1) ss += __shfl_xor(ss, off);
  float r = rsqrtf(ss * (1.f / 128.f) + 1e-5f);
  int c0 = (int)((base + t) & 1023), c1 = (int)((base + t + 64) & 1023);
  float ga = 1.f / (1.f + expf(-(g2raw[base + t] + bg2[c0])));
  float gb = 1.f / (1.f + expf(-(g2raw[base + t + 64] + bg2[c1])));
  ob[base + t] = f2bf(a * r * wn[t] * ga);
  ob[base + t + 64] = f2bf(b * r * wn[t + 64] * gb);
}

extern "C" void kernel_launch(void* const* d_in, const int* in_sizes, int n_in,
                              void* d_out, int out_size, void* d_ws, size_t ws_size,
                              hipStream_t stream) {
  const float* x = (const float*)d_in[0];
  const float* ve = (const float*)d_in[1];
  const float* lam = (const float*)d_in[2];
  const float* Wq = (const float*)d_in[3];
  const float* Wk = (const float*)d_in[4];
  const float* Wv = (const float*)d_in[5];
  const float* Wo = (const float*)d_in[6];
  const float* wq_conv = (const float*)d_in[7];
  const float* wk_conv = (const float*)d_in[8];
  const float* wv_conv = (const float*)d_in[9];
  const float* Wf1 = (const float*)d_in[10];
  const float* Wf2 = (const float*)d_in[11];
  const float* Wb = (const float*)d_in[12];
  const float* A_log = (const float*)d_in[13];
  const float* dt_bias = (const float*)d_in[14];
  const float* Wg1 = (const float*)d_in[15];
  const float* Wg2 = (const float*)d_in[16];
  const float* bg2 = (const float*)d_in[17];
  const float* w_norm = (const float*)d_in[18];
  float* out = (float*)d_out;

  float* ws = (float*)d_ws;
  const size_t SZ = (size_t)S_LEN * KD_;  // 2M floats
  float* q_pre = ws;
  float* k_pre = ws + SZ;
  float* v_pre = ws + 2 * SZ;
  float* ve_pre = ws + 3 * SZ;
  float* q_c = ws + 4 * SZ;
  float* k_c = ws + 5 * SZ;
  float* v_mix = ws + 6 * SZ;
  float* f1 = ve_pre;
  float* bpre = ve_pre + 2 * (size_t)S_LEN * DV_;  // [S,8] raw
  float* graw = q_pre;                             // -> raw g in place
  float* g2raw = k_pre;                            // raw gate pre-activation
  float* o_buf = v_pre;
  uint16_t* bws = (uint16_t*)(ws + 7 * SZ);
  uint16_t* xb = bws;
  uint16_t* veb = xb + SZ;
  uint16_t* Wqb = veb + SZ;
  uint16_t* Wkb = Wqb + (size_t)KD_ * DMODEL;
  uint16_t* Wvb = Wkb + (size_t)KD_ * DMODEL;
  uint16_t* Wob = Wvb + (size_t)KD_ * DMODEL;
  uint16_t* Wg1b = Wob + (size_t)DMODEL * KD_;
  uint16_t* Wg2b = Wg1b + (size_t)DV_ * DMODEL;
  uint16_t* g1b = Wg2b + (size_t)KD_ * DV_;
  uint16_t* ob = g1b + (size_t)S_LEN * DV_;
  // pre buffers in proven-safe region (starts at 20M floats = 80MB)
  float* preF = ws + (size_t)20 * 1024 * 1024;                  // 512*128 floats
  uint16_t* preB = (uint16_t*)(ws + (size_t)20 * 1024 * 1024 + 65536 + 64);

  dim3 blk(256);
  int ew_blocks = (S_LEN * KD_ + 255) / 256;

  CastArgs ca;
  ca.s[0] = x;   ca.d[0] = xb;   ca.n[0] = S_LEN * DMODEL;
  ca.s[1] = ve;  ca.d[1] = veb;  ca.n[1] = S_LEN * DMODEL;
  ca.s[2] = Wq;  ca.d[2] = Wqb;  ca.n[2] = KD_ * DMODEL;
  ca.s[3] = Wk;  ca.d[3] = Wkb;  ca.n[3] = KD_ * DMODEL;
  ca.s[4] = Wv;  ca.d[4] = Wvb;  ca.n[4] = KD_ * DMODEL;
  ca.s[5] = Wo;  ca.d[5] = Wob;  ca.n[5] = DMODEL * KD_;
  ca.s[6] = Wg1; ca.d[6] = Wg1b; ca.n[6] = DV_ * DMODEL;
  ca.s[7] = Wg2; ca.d[7] = Wg2b; ca.n[7] = KD_ * DV_;
  cast_multi<<<dim3(1024, 8), blk, 0, stream>>>(ca);

  GJobs jq;
  jq.A[0] = xb;  jq.B[0] = Wqb;  jq.C[0] = q_pre;  jq.N[0] = KD_; jq.outbf[0] = 0;
  jq.A[1] = xb;  jq.B[1] = Wkb;  jq.C[1] = k_pre;  jq.N[1] = KD_; jq.outbf[1] = 0;
  jq.A[2] = xb;  jq.B[2] = Wvb;  jq.C[2] = v_pre;  jq.N[2] = KD_; jq.outbf[2] = 0;
  jq.A[3] = veb; jq.B[3] = Wvb;  jq.C[3] = ve_pre; jq.N[3] = KD_; jq.outbf[3] = 0;
  jq.A[4] = xb;  jq.B[4] = Wg1b; jq.C[4] = g1b;    jq.N[4] = DV_; jq.outbf[4] = 1;
  gemm_mfma<<<dim3(8, 16, 5), blk, 0, stream>>>(jq, DMODEL);

  conv_silu_mix<<<ew_blocks, blk, 0, stream>>>(q_pre, k_pre, v_pre, ve_pre,
                                               wq_conv, wk_conv, wv_conv, lam,
                                               q_c, k_c, v_mix);

  gemm_abt<<<dim3(2, 32), blk, 0, stream>>>(x, Wf1, f1, S_LEN, DV_, DMODEL);
  gemm_abt<<<dim3(1, 32), blk, 0, stream>>>(x, Wb, bpre, S_LEN, NH, DMODEL);
  gemm_abt<<<dim3(16, 32), blk, 0, stream>>>(f1, Wf2, graw, S_LEN, KD_, DV_);
  g_only<<<ew_blocks, blk, 0, stream>>>(graw, dt_bias, A_log);

  kda_pre<<<dim3(NW2 * 8), blk, 0, stream>>>(q_c, k_c, graw, v_mix, bpre,
                                             preB, preF);
  kda_scan<<<dim3(64), dim3(128), 0, stream>>>(preB, preF, o_buf);

  GJobs jg2;
  jg2.A[0] = g1b; jg2.B[0] = Wg2b; jg2.C[0] = g2raw; jg2.N[0] = KD_; jg2.outbf[0] = 0;
  gemm_mfma<<<dim3(8, 16, 1), blk, 0, stream>>>(jg2, DV_);

  gated_rmsnorm<<<dim3(S_LEN * NH), dim3(64), 0, stream>>>(o_buf, g2raw, bg2,
                                                           w_norm, ob);

  GJobs jo;
  jo.A[0] = ob; jo.B[0] = Wob; jo.C[0] = out; jo.N[0] = DMODEL; jo.outbf[0] = 0;
  gemm_mfma<<<dim3(8, 16, 1), blk, 0, stream>>>(jo, KD_);
}